// Round 5
// baseline (397.747 us; speedup 1.0000x reference)
//
#include <hip/hip_runtime.h>
#include <math.h>

#define NSL 0.2f   // leaky relu negative slope
#define IN_DIM 165
#define HID 128
#define OUT_H 64
#define NCB_MAX 512 // max coarse buckets (N <= 131072)
#define EPB 4096    // edges per pass1 block
#define NB 4        // source-range buckets (row>>15); 32K rows * 128 B = 4 MiB = one XCD L2
#define NPQ 9       // max nodes per quarter-wave, gcn gather (768 blk * 16 qw * 9 >= 110592)
#define NPG 5       // max nodes per 8-lane group, gat     (768 blk * 32 qw * 5 >= 122880)

typedef __attribute__((ext_vector_type(8))) short bf16x8;
typedef __attribute__((ext_vector_type(4))) float f32x4;

// ---------- bf16 pack (round-to-nearest-even) ----------
__device__ inline unsigned pack_bf16(float a, float b) {
    unsigned ua = __float_as_uint(a);
    ua += 0x7FFFu + ((ua >> 16) & 1u);
    unsigned ub = __float_as_uint(b);
    ub += 0x7FFFu + ((ub >> 16) & 1u);
    return (ua >> 16) | (ub & 0xFFFF0000u);
}

// column permutation of the packed layouts: stored bf16 index i -> original col.
__device__ __host__ inline int pcol(int i) {
    int j = i >> 1, odd = i & 1;
    return 32 * (j >> 4) + (j & 15) + 16 * odd;
}

// ---------- coarse histogram (LDS-privatized) ----------
__global__ __launch_bounds__(256) void chist(const int* __restrict__ coli, int E,
                                             int* __restrict__ ghist, int ncb) {
    __shared__ int h[NCB_MAX];
    for (int i = threadIdx.x; i < ncb; i += 256) h[i] = 0;
    __syncthreads();
    int e0 = blockIdx.x * EPB;
    int e1 = min(e0 + EPB, E);
    for (int e = e0 + threadIdx.x; e < e1; e += 256)
        atomicAdd(&h[coli[e] >> 8], 1);
    __syncthreads();
    for (int i = threadIdx.x; i < ncb; i += 256)
        if (h[i]) atomicAdd(&ghist[i], h[i]);
}

// ---------- 1-block scan of coarse histogram -> cstart, gcursor ----------
__global__ __launch_bounds__(NCB_MAX) void cscan(const int* __restrict__ ghist,
                                                 int* __restrict__ cstart,
                                                 int* __restrict__ gcursor,
                                                 int ncb, int E) {
    __shared__ int tmp[NCB_MAX];
    int tid = threadIdx.x;
    int v = (tid < ncb) ? ghist[tid] : 0;
    tmp[tid] = v;
    __syncthreads();
    for (int off = 1; off < NCB_MAX; off <<= 1) {
        int t = (tid >= off) ? tmp[tid - off] : 0;
        __syncthreads();
        tmp[tid] += t;
        __syncthreads();
    }
    if (tid < ncb) {
        int excl = tmp[tid] - v;
        cstart[tid] = excl;
        gcursor[tid] = excl;
    }
    if (tid == ncb - 1) cstart[ncb] = E;
}

// ---------- pass1: block-privatized scatter into coarse buckets ----------
// ebuf value = (row << 8) | (col & 255)   (requires N < 2^24)
__global__ __launch_bounds__(256) void pass1_scatter(const int* __restrict__ rowi,
                                                     const int* __restrict__ coli, int E,
                                                     int* __restrict__ gcursor,
                                                     unsigned* __restrict__ ebuf, int ncb) {
    __shared__ int hist[NCB_MAX];
    __shared__ int base[NCB_MAX];
    int e0 = blockIdx.x * EPB;
    int e1 = min(e0 + EPB, E);
    for (int i = threadIdx.x; i < ncb; i += 256) hist[i] = 0;
    __syncthreads();
    for (int e = e0 + threadIdx.x; e < e1; e += 256)
        atomicAdd(&hist[coli[e] >> 8], 1);
    __syncthreads();
    for (int i = threadIdx.x; i < ncb; i += 256) {
        int h = hist[i];
        base[i] = h ? atomicAdd(&gcursor[i], h) : 0;
        hist[i] = 0;
    }
    __syncthreads();
    for (int e = e0 + threadIdx.x; e < e1; e += 256) {
        int c = coli[e];
        int cb = c >> 8;
        int rank = atomicAdd(&hist[cb], 1);
        ebuf[base[cb] + rank] = ((unsigned)rowi[e] << 8) | (unsigned)(c & 255);
    }
}

// ---------- fused pass2: 1024-key counting sort by (node, src-bucket) ----------
// key = (local<<2) | srcbucket(row).  csr stays node-contiguous (node-major,
// bucket-minor), so offsets[node] semantics are preserved; offsets2[node*4+b]
// adds per-bucket sublist boundaries for the phased gathers.
__global__ __launch_bounds__(256) void pass2_all(const unsigned* __restrict__ ebuf,
                                                 const int* __restrict__ cstart,
                                                 int* __restrict__ offsets,
                                                 int* __restrict__ offsets2,
                                                 float* __restrict__ dinv,
                                                 int* __restrict__ csr_src,
                                                 int n, int E) {
    __shared__ int cnt[1024];
    __shared__ int kb[1024];
    __shared__ int scn[256];
    const int tid = threadIdx.x;
    const int cb = blockIdx.x;
#pragma unroll
    for (int j = 0; j < 4; j++) cnt[tid * 4 + j] = 0;
    __syncthreads();
    int s = cstart[cb], e1 = cstart[cb + 1];
    for (int e = s + tid; e < e1; e += 256) {
        unsigned u = ebuf[e];
        int key = ((u & 255u) << 2) | ((u >> 23) & 3u);
        atomicAdd(&cnt[key], 1);
    }
    __syncthreads();
    int c0 = cnt[tid * 4], c1 = cnt[tid * 4 + 1], c2 = cnt[tid * 4 + 2], c3 = cnt[tid * 4 + 3];
    int v = c0 + c1 + c2 + c3;
    scn[tid] = v;
    __syncthreads();
#pragma unroll
    for (int off = 1; off < 256; off <<= 1) {
        int t = (tid >= off) ? scn[tid - off] : 0;
        __syncthreads();
        scn[tid] += t;
        __syncthreads();
    }
    int base = s + scn[tid] - v;   // global exclusive offset for this node
    kb[tid * 4]     = base;
    kb[tid * 4 + 1] = base + c0;
    kb[tid * 4 + 2] = base + c0 + c1;
    kb[tid * 4 + 3] = base + c0 + c1 + c2;
    int node = (cb << 8) + tid;
    if (node < n) {
        offsets[node] = base;
        offsets2[node * 4]     = base;
        offsets2[node * 4 + 1] = base + c0;
        offsets2[node * 4 + 2] = base + c0 + c1;
        offsets2[node * 4 + 3] = base + c0 + c1 + c2;
        dinv[node] = rsqrtf((float)v + 1.0f);   // +1 = self loop
    }
    if (cb == 0 && tid == 0) { offsets[n] = E; offsets2[4 * n] = E; }
#pragma unroll
    for (int j = 0; j < 4; j++) cnt[tid * 4 + j] = 0;
    __syncthreads();
    for (int e = s + tid; e < e1; e += 256) {
        unsigned u = ebuf[e];
        int key = ((u & 255u) << 2) | ((u >> 23) & 3u);
        int rank = atomicAdd(&cnt[key], 1);
        csr_src[kb[key] + rank] = (int)(u >> 8);
    }
}

// ---------- weight prep (one dispatch): W1/Wg bf16 fragments + permuted b1/bg/Wfc ----------
__global__ __launch_bounds__(256) void wprep_all(const float* __restrict__ W1,
                                                 const float* __restrict__ b1,
                                                 const float* __restrict__ Wg,
                                                 const float* __restrict__ bg,
                                                 const float* __restrict__ Wfc,
                                                 uint4* __restrict__ wfrag,
                                                 float* __restrict__ b1p,
                                                 uint4* __restrict__ wg2frag,
                                                 float* __restrict__ bgp,
                                                 float2* __restrict__ wfcp) {
    int idx = blockIdx.x * 256 + threadIdx.x;
    if (idx < 3072) {
        int q = idx & 3, n = (idx >> 2) & 127, c = idx >> 9;
        int k0 = c * 32 + q * 8;
        float f[8];
#pragma unroll
        for (int j = 0; j < 8; j++) {
            int k = k0 + j;
            f[j] = (k < IN_DIM) ? W1[k * 128 + n] : 0.f;
        }
        uint4 u;
        u.x = pack_bf16(f[0], f[1]);
        u.y = pack_bf16(f[2], f[3]);
        u.z = pack_bf16(f[4], f[5]);
        u.w = pack_bf16(f[6], f[7]);
        wfrag[idx] = u;
    } else if (idx < 4096) {
        int i2 = idx - 3072;
        int q = i2 & 3, n = (i2 >> 2) & 63, c = i2 >> 8;
        float f[8];
#pragma unroll
        for (int j = 0; j < 8; j++) {
            int ks = c * 32 + q * 8 + j;
            f[j] = Wg[pcol(ks) * 64 + n];
        }
        uint4 u;
        u.x = pack_bf16(f[0], f[1]);
        u.y = pack_bf16(f[2], f[3]);
        u.z = pack_bf16(f[4], f[5]);
        u.w = pack_bf16(f[6], f[7]);
        wg2frag[i2] = u;
    }
    if (idx < 128) b1p[idx] = b1[pcol(idx)];
    if (idx < 64) {
        int o = pcol(idx);
        bgp[idx] = bg[o];
        wfcp[idx] = make_float2(Wfc[o * 2], Wfc[o * 2 + 1]);
    }
}

// ---------- GEMM1 via bf16 MFMA, LDS-free, x read directly (fused cvt) ----------
// Epilogue: int8 quantization, one f32 scale per row (h1s, L2-resident).
__global__ __launch_bounds__(256) void gemm1_mfma(const float* __restrict__ x,
                                                  const uint4* __restrict__ wfrag,
                                                  const float* __restrict__ dinv,
                                                  unsigned char* __restrict__ h1p8,
                                                  float* __restrict__ h1s, int M) {
    const int t = threadIdx.x;
    const int wave = t >> 6;
    const int lane = t & 63;
    const int l16 = lane & 15;
    const int quad = lane >> 4;
    const int rowbase = blockIdx.x * 64 + wave * 16;

    int arow = rowbase + l16;
    if (arow >= M) arow = M - 1;
    const float* xr = x + (size_t)arow * IN_DIM;

    f32x4 acc[8];
#pragma unroll
    for (int nt = 0; nt < 8; nt++) acc[nt] = (f32x4){0.f, 0.f, 0.f, 0.f};

#pragma unroll
    for (int c = 0; c < 6; c++) {
        int k0 = c * 32 + quad * 8;
        float f[8];
#pragma unroll
        for (int j = 0; j < 8; j++)
            f[j] = (k0 + j < IN_DIM) ? xr[k0 + j] : 0.f;
        uint4 au;
        au.x = pack_bf16(f[0], f[1]);
        au.y = pack_bf16(f[2], f[3]);
        au.z = pack_bf16(f[4], f[5]);
        au.w = pack_bf16(f[6], f[7]);
        bf16x8 a = __builtin_bit_cast(bf16x8, au);
#pragma unroll
        for (int nt = 0; nt < 8; nt++) {
            uint4 bu = wfrag[(size_t)((c * 128 + nt * 16 + l16) * 4 + quad)];
            bf16x8 b = __builtin_bit_cast(bf16x8, bu);
            acc[nt] = __builtin_amdgcn_mfma_f32_16x16x32_bf16(a, b, acc[nt], 0, 0, 0);
        }
    }

#pragma unroll
    for (int r = 0; r < 4; r++) {
        int row = rowbase + quad * 4 + r;
        if (row < M) {
            float s = dinv[row];
            float v[8];
#pragma unroll
            for (int nt = 0; nt < 8; nt++) v[nt] = acc[nt][r] * s;
            float gm = fabsf(v[0]);
#pragma unroll
            for (int nt = 1; nt < 8; nt++) gm = fmaxf(gm, fabsf(v[nt]));
            gm = fmaxf(gm, __shfl_xor(gm, 1, 16));
            gm = fmaxf(gm, __shfl_xor(gm, 2, 16));
            gm = fmaxf(gm, __shfl_xor(gm, 4, 16));
            gm = fmaxf(gm, __shfl_xor(gm, 8, 16));
            float inv = gm > 0.f ? 127.0f / gm : 0.f;
            unsigned short* hr = (unsigned short*)(h1p8 + (size_t)row * 128);
#pragma unroll
            for (int p = 0; p < 4; p++) {
                int q0 = (int)rintf(v[2 * p] * inv);
                int q1 = (int)rintf(v[2 * p + 1] * inv);
                hr[p * 16 + l16] = (unsigned short)((q0 & 0xff) | ((q1 & 0xff) << 8));
            }
            if (l16 == 0) h1s[row] = gm * (1.0f / 127.0f);
        }
    }
}

// 8 int8 -> f32, scaled accumulate (s = row scale)
__device__ inline void fma8i8(float* a, uint2 u, float s) {
    a[0] = fmaf((float)(char)(u.x), s, a[0]);
    a[1] = fmaf((float)(char)(u.x >> 8), s, a[1]);
    a[2] = fmaf((float)(char)(u.x >> 16), s, a[2]);
    a[3] = fmaf((float)(char)(u.x >> 24), s, a[3]);
    a[4] = fmaf((float)(char)(u.y), s, a[4]);
    a[5] = fmaf((float)(char)(u.y >> 8), s, a[5]);
    a[6] = fmaf((float)(char)(u.y >> 16), s, a[6]);
    a[7] = fmaf((float)(char)(u.y >> 24), s, a[7]);
}

__device__ inline void fma8(float* a, uint4 u, float w) {
    a[0] = fmaf(__uint_as_float(u.x << 16), w, a[0]);
    a[1] = fmaf(__uint_as_float(u.x & 0xFFFF0000u), w, a[1]);
    a[2] = fmaf(__uint_as_float(u.y << 16), w, a[2]);
    a[3] = fmaf(__uint_as_float(u.y & 0xFFFF0000u), w, a[3]);
    a[4] = fmaf(__uint_as_float(u.z << 16), w, a[4]);
    a[5] = fmaf(__uint_as_float(u.z & 0xFFFF0000u), w, a[5]);
    a[6] = fmaf(__uint_as_float(u.w << 16), w, a[6]);
    a[7] = fmaf(__uint_as_float(u.w & 0xFFFF0000u), w, a[7]);
}

__device__ inline float lexp(float e) {
    e = e > 0.f ? e : NSL * e;
    return __expf(e);
}

// ---------- GCN gather, src-range phased ----------
// Co-resident grid (3 blocks/CU uniform). Each quarter-wave owns a balanced
// contiguous node range; all blocks sweep the 4 source buckets in lockstep
// (per-block __syncthreads per phase; blocks co-start and have ±2% work
// variance -> wall-clock aligned). Per phase, the active 4 MiB source slab
// fits one XCD L2, removing capacity misses (141 MB -> ~cold floor 88 MB).
__global__ __launch_bounds__(256, 3) void gcn_gather(const int* __restrict__ offsets2,
                                                     const int* __restrict__ csr_src,
                                                     const uint2* __restrict__ h1v8,
                                                     const float* __restrict__ h1s,
                                                     const float* __restrict__ dinv,
                                                     const float* __restrict__ b1p,
                                                     uint4* __restrict__ gb,
                                                     int totq, int n) {
    int qid = (blockIdx.x << 4) + (threadIdx.x >> 4);
    int lane = threadIdx.x & 15;
    int nstart = (int)((long long)qid * n / totq);
    int nend   = (int)((long long)(qid + 1) * n / totq);

    float acc[NPQ][8];
#pragma unroll
    for (int i = 0; i < NPQ; i++)
#pragma unroll
        for (int j = 0; j < 8; j++) acc[i][j] = 0.f;

    for (int b = 0; b < NB; b++) {
#pragma unroll
        for (int i = 0; i < NPQ; i++) {
            int node = nstart + i;
            if (node < nend) {
                int k  = offsets2[(node << 2) | b];
                int e1 = offsets2[((node << 2) | b) + 1];
                for (; k + 4 <= e1; k += 4) {
                    int r0 = csr_src[k], r1 = csr_src[k + 1];
                    int r2 = csr_src[k + 2], r3 = csr_src[k + 3];
                    uint2 v0 = h1v8[(size_t)r0 * 16 + lane];
                    uint2 v1 = h1v8[(size_t)r1 * 16 + lane];
                    uint2 v2 = h1v8[(size_t)r2 * 16 + lane];
                    uint2 v3 = h1v8[(size_t)r3 * 16 + lane];
                    float w0 = h1s[r0], w1 = h1s[r1], w2 = h1s[r2], w3 = h1s[r3];
                    fma8i8(acc[i], v0, w0);
                    fma8i8(acc[i], v1, w1);
                    fma8i8(acc[i], v2, w2);
                    fma8i8(acc[i], v3, w3);
                }
                for (; k < e1; k++) {
                    int r = csr_src[k];
                    fma8i8(acc[i], h1v8[(size_t)r * 16 + lane], h1s[r]);
                }
            }
        }
        __syncthreads();
    }

#pragma unroll
    for (int i = 0; i < NPQ; i++) {
        int node = nstart + i;
        if (node < nend) {
            fma8i8(acc[i], h1v8[(size_t)node * 16 + lane], h1s[node]);   // self loop
            float dc = dinv[node];
            float4 bb0 = ((const float4*)b1p)[lane * 2];
            float4 bb1 = ((const float4*)b1p)[lane * 2 + 1];
            float o[8];
            o[0] = fmaxf(acc[i][0] * dc + bb0.x, 0.f);
            o[1] = fmaxf(acc[i][1] * dc + bb0.y, 0.f);
            o[2] = fmaxf(acc[i][2] * dc + bb0.z, 0.f);
            o[3] = fmaxf(acc[i][3] * dc + bb0.w, 0.f);
            o[4] = fmaxf(acc[i][4] * dc + bb1.x, 0.f);
            o[5] = fmaxf(acc[i][5] * dc + bb1.y, 0.f);
            o[6] = fmaxf(acc[i][6] * dc + bb1.z, 0.f);
            o[7] = fmaxf(acc[i][7] * dc + bb1.w, 0.f);
            uint4 pk;
            pk.x = pack_bf16(o[0], o[1]);
            pk.y = pack_bf16(o[2], o[3]);
            pk.z = pack_bf16(o[4], o[5]);
            pk.w = pack_bf16(o[6], o[7]);
            gb[(size_t)node * 16 + lane] = pk;
        }
    }
}

// ---------- GEMM2 via bf16 MFMA, LDS-free; fused es/ed; bf16 h2 out ----------
__global__ __launch_bounds__(256) void gemm2_mfma(const uint4* __restrict__ gb4,
                                                  const uint4* __restrict__ wg2frag,
                                                  const float* __restrict__ a_src,
                                                  const float* __restrict__ a_dst,
                                                  unsigned* __restrict__ h2b,
                                                  float* __restrict__ es,
                                                  float* __restrict__ ed, int M) {
    const int t = threadIdx.x;
    const int wave = t >> 6;
    const int lane = t & 63;
    const int l16 = lane & 15;
    const int quad = lane >> 4;
    const int rowbase = blockIdx.x * 64 + wave * 16;

    int arow = rowbase + l16;
    if (arow >= M) arow = M - 1;

    f32x4 acc[4];
#pragma unroll
    for (int nt = 0; nt < 4; nt++) acc[nt] = (f32x4){0.f, 0.f, 0.f, 0.f};

#pragma unroll
    for (int c = 0; c < 4; c++) {
        uint4 au = gb4[(size_t)arow * 16 + c * 4 + quad];
        bf16x8 a = __builtin_bit_cast(bf16x8, au);
#pragma unroll
        for (int nt = 0; nt < 4; nt++) {
            uint4 bu = wg2frag[(size_t)((c * 64 + nt * 16 + l16) * 4 + quad)];
            bf16x8 b = __builtin_bit_cast(bf16x8, bu);
            acc[nt] = __builtin_amdgcn_mfma_f32_16x16x32_bf16(a, b, acc[nt], 0, 0, 0);
        }
    }

    float as0 = a_src[l16], as1 = a_src[16 + l16], as2 = a_src[32 + l16], as3 = a_src[48 + l16];
    float ad0 = a_dst[l16], ad1 = a_dst[16 + l16], ad2 = a_dst[32 + l16], ad3 = a_dst[48 + l16];

#pragma unroll
    for (int r = 0; r < 4; r++) {
        int row = rowbase + quad * 4 + r;
        float ps = acc[0][r] * as0 + acc[1][r] * as1 + acc[2][r] * as2 + acc[3][r] * as3;
        float pd = acc[0][r] * ad0 + acc[1][r] * ad1 + acc[2][r] * ad2 + acc[3][r] * ad3;
#pragma unroll
        for (int m = 8; m; m >>= 1) {
            ps += __shfl_xor(ps, m, 16);
            pd += __shfl_xor(pd, m, 16);
        }
        if (row < M) {
            h2b[(size_t)row * 32 + l16]      = pack_bf16(acc[0][r], acc[1][r]);
            h2b[(size_t)row * 32 + 16 + l16] = pack_bf16(acc[2][r], acc[3][r]);
            if (l16 == 0) { es[row] = ps; ed[row] = pd; }
        }
    }
}

// ---------- fused GAT, src-range phased (same mechanism as gcn_gather) ----------
__global__ __launch_bounds__(256, 3) void gat_fused(const int* __restrict__ offsets2,
                                                    const int* __restrict__ csr_src,
                                                    const uint4* __restrict__ h2v,  // row = 8 uint4
                                                    const float* __restrict__ es,
                                                    const float* __restrict__ ed,
                                                    const float* __restrict__ bgp,
                                                    const float2* __restrict__ wfcp,
                                                    const float* __restrict__ bfc,
                                                    float* __restrict__ out,
                                                    int totq, int n) {
    int qid = (blockIdx.x << 5) + (threadIdx.x >> 3);
    int lane = threadIdx.x & 7;
    int nstart = (int)((long long)qid * n / totq);
    int nend   = (int)((long long)(qid + 1) * n / totq);

    float acc[NPG][8];
    float ssum[NPG];
    float edc[NPG];
#pragma unroll
    for (int i = 0; i < NPG; i++) {
        ssum[i] = 0.f;
        int node = nstart + i;
        edc[i] = (node < nend) ? ed[node] : 0.f;
#pragma unroll
        for (int j = 0; j < 8; j++) acc[i][j] = 0.f;
    }

    for (int b = 0; b < NB; b++) {
#pragma unroll
        for (int i = 0; i < NPG; i++) {
            int node = nstart + i;
            if (node < nend) {
                int k  = offsets2[(node << 2) | b];
                int e1 = offsets2[((node << 2) | b) + 1];
                float ec = edc[i];
                for (; k + 4 <= e1; k += 4) {
                    int r0 = csr_src[k], r1 = csr_src[k + 1];
                    int r2 = csr_src[k + 2], r3 = csr_src[k + 3];
                    float e0 = es[r0], e1f = es[r1], e2 = es[r2], e3 = es[r3];
                    uint4 v0 = h2v[(size_t)r0 * 8 + lane];
                    uint4 v1 = h2v[(size_t)r1 * 8 + lane];
                    uint4 v2 = h2v[(size_t)r2 * 8 + lane];
                    uint4 v3 = h2v[(size_t)r3 * 8 + lane];
                    float x0 = lexp(e0 + ec), x1 = lexp(e1f + ec);
                    float x2 = lexp(e2 + ec), x3 = lexp(e3 + ec);
                    ssum[i] += (x0 + x1) + (x2 + x3);
                    fma8(acc[i], v0, x0);
                    fma8(acc[i], v1, x1);
                    fma8(acc[i], v2, x2);
                    fma8(acc[i], v3, x3);
                }
                for (; k < e1; k++) {
                    int r = csr_src[k];
                    float xv = lexp(es[r] + ec);
                    ssum[i] += xv;
                    fma8(acc[i], h2v[(size_t)r * 8 + lane], xv);
                }
            }
        }
        __syncthreads();
    }

#pragma unroll
    for (int i = 0; i < NPG; i++) {
        int node = nstart + i;
        if (node < nend) {
            float x0s = lexp(es[node] + edc[i]);          // self loop
            fma8(acc[i], h2v[(size_t)node * 8 + lane], x0s);
            float rcp = 1.0f / (ssum[i] + x0s);
            float4 b0 = ((const float4*)bgp)[lane * 2];
            float4 b1 = ((const float4*)bgp)[lane * 2 + 1];
            float o[8];
            o[0] = fmaxf(acc[i][0] * rcp + b0.x, 0.f);
            o[1] = fmaxf(acc[i][1] * rcp + b0.y, 0.f);
            o[2] = fmaxf(acc[i][2] * rcp + b0.z, 0.f);
            o[3] = fmaxf(acc[i][3] * rcp + b0.w, 0.f);
            o[4] = fmaxf(acc[i][4] * rcp + b1.x, 0.f);
            o[5] = fmaxf(acc[i][5] * rcp + b1.y, 0.f);
            o[6] = fmaxf(acc[i][6] * rcp + b1.z, 0.f);
            o[7] = fmaxf(acc[i][7] * rcp + b1.w, 0.f);

            float p0 = 0.f, p1 = 0.f;
#pragma unroll
            for (int m2 = 0; m2 < 4; m2++) {
                float4 w = ((const float4*)wfcp)[lane * 4 + m2];
                p0 += o[2 * m2] * w.x + o[2 * m2 + 1] * w.z;
                p1 += o[2 * m2] * w.y + o[2 * m2 + 1] * w.w;
            }
#pragma unroll
            for (int m = 4; m; m >>= 1) {
                p0 += __shfl_xor(p0, m, 8);
                p1 += __shfl_xor(p1, m, 8);
            }
            if (lane == 0) {
                out[(size_t)node * 2 + 0] = p0 + bfc[0];
                out[(size_t)node * 2 + 1] = p1 + bfc[1];
            }
        }
    }
}

extern "C" void kernel_launch(void* const* d_in, const int* in_sizes, int n_in,
                              void* d_out, int out_size, void* d_ws, size_t ws_size,
                              hipStream_t stream) {
    const float* x     = (const float*)d_in[0];
    const int*   ei    = (const int*)d_in[1];
    const float* W1    = (const float*)d_in[2];
    const float* b1    = (const float*)d_in[3];
    const float* Wg    = (const float*)d_in[4];
    const float* a_src = (const float*)d_in[5];
    const float* a_dst = (const float*)d_in[6];
    const float* bg    = (const float*)d_in[7];
    const float* Wfc   = (const float*)d_in[8];
    const float* bfc   = (const float*)d_in[9];
    float* out = (float*)d_out;

    const int N = in_sizes[0] / IN_DIM;
    const int E = in_sizes[1] / 2;
    const int* rowi = ei;
    const int* coli = ei + E;
    const int ncb = (N + 255) >> 8;            // coarse buckets of 256 nodes

    auto alignup = [](char* p) { return (char*)(((uintptr_t)p + 15) & ~(uintptr_t)15); };

    // workspace layout
    char* wsb = (char*)d_ws;
    int*   offsets  = (int*)wsb;                        // N+8
    int*   offsets2 = offsets + N + 8;                  // 4N+8 (per src-bucket)
    float* dinv    = (float*)(offsets2 + 4 * N + 8);    // N
    float* es      = dinv + N;                          // N
    float* ed      = es + N;                            // N
    float* h1s     = ed + N;                            // N (f32 row scales, 400 KB)
    int*   ghist   = (int*)(h1s + N);                   // NCB_MAX
    int*   cstart  = ghist + NCB_MAX;                   // NCB_MAX+2
    int*   gcursor = cstart + NCB_MAX + 2;              // NCB_MAX
    float* b1p     = (float*)(gcursor + NCB_MAX);       // 128
    float* bgp     = b1p + 128;                         // 64
    float2* wfcp   = (float2*)(bgp + 64);               // 64 float2
    uint4* wfrag   = (uint4*)alignup((char*)(wfcp + 64));   // 3072 uint4 (48 KB)
    uint4* wg2frag = wfrag + 3072;                      // 1024 uint4 (16 KB)
    int*   csr_src = (int*)(wg2frag + 1024);            // E
    unsigned* ebuf = (unsigned*)(csr_src + E);          // E (packed row<<8|local)
    unsigned char* h1p8 = (unsigned char*)alignup((char*)(ebuf + E)); // N*128 bytes (int8, perm)
    uint4* gb      = (uint4*)alignup((char*)(h1p8 + (size_t)N * 128)); // N*16 uint4
    unsigned* h2b  = (unsigned*)h1p8;  // alias: h1p8 dead after gcn_gather; h2b = N*32 words

    hipMemsetAsync(ghist, 0, NCB_MAX * 4, stream);

    const int nbE = (E + EPB - 1) / EPB;

    // 1) CSR build: coarse hist -> scan -> privatized scatter -> fused fine sort
    chist<<<nbE, 256, 0, stream>>>(coli, E, ghist, ncb);
    cscan<<<1, NCB_MAX, 0, stream>>>(ghist, cstart, gcursor, ncb, E);
    pass1_scatter<<<nbE, 256, 0, stream>>>(rowi, coli, E, gcursor, ebuf, ncb);
    pass2_all<<<ncb, 256, 0, stream>>>(ebuf, cstart, offsets, offsets2, dinv, csr_src, N, E);

    // 2) weight prep (single dispatch)
    wprep_all<<<16, 256, 0, stream>>>(W1, b1, Wg, bg, Wfc, wfrag, b1p, wg2frag, bgp, wfcp);

    // 3) h1p8 = int8-row-quant((x @ W1) * dinv[row]) via LDS-free MFMA
    gemm1_mfma<<<(N + 63) / 64, 256, 0, stream>>>(x, wfrag, dinv, h1p8, h1s, N);

    // 4) GCN gather, phased over 4 source ranges (co-resident grid, 3 blocks/CU)
    int gblocks = 768;
    while ((long long)gblocks * 16 * NPQ < (long long)N) gblocks += 256;
    gcn_gather<<<gblocks, 256, 0, stream>>>(offsets2, csr_src, (const uint2*)h1p8,
                                            h1s, dinv, b1p, gb, gblocks * 16, N);

    // 5) h2b = bf16(g @ Wg) via LDS-free MFMA, fused es/ed epilogue
    gemm2_mfma<<<(N + 63) / 64, 256, 0, stream>>>(gb, wg2frag, a_src, a_dst, h2b, es, ed, N);

    // 6) fused GAT, phased over 4 source ranges
    int ablocks = 768;
    while ((long long)ablocks * 32 * NPG < (long long)N) ablocks += 256;
    gat_fused<<<ablocks, 256, 0, stream>>>(offsets2, csr_src, (const uint4*)h2b,
                                           es, ed, bgp, wfcp, bfc, out, ablocks * 32, N);
}

// Round 6
// 355.561 us; speedup vs baseline: 1.1186x; 1.1186x over previous
//
#include <hip/hip_runtime.h>
#include <math.h>

#define NSL 0.2f   // leaky relu negative slope
#define IN_DIM 165
#define HID 128
#define OUT_H 64
#define NCB_MAX 512 // max coarse buckets (N <= 131072)
#define EPB 4096    // edges per pass1 block
#define NB 4        // source-range buckets (row>>15); 32K rows * 128 B = 4 MiB = one XCD L2
#define NPQ 7       // max nodes per quarter-wave, gcn gather (1024 blk * 16 qw * 7 >= 114688)
#define NPG 4       // max nodes per 8-lane group, gat      (1024 blk * 32 qw * 4 >= 131072)

typedef __attribute__((ext_vector_type(8))) short bf16x8;
typedef __attribute__((ext_vector_type(4))) float f32x4;

// ---------- bf16 pack (round-to-nearest-even) ----------
__device__ inline unsigned pack_bf16(float a, float b) {
    unsigned ua = __float_as_uint(a);
    ua += 0x7FFFu + ((ua >> 16) & 1u);
    unsigned ub = __float_as_uint(b);
    ub += 0x7FFFu + ((ub >> 16) & 1u);
    return (ua >> 16) | (ub & 0xFFFF0000u);
}

// column permutation of the packed layouts: stored bf16 index i -> original col.
__device__ __host__ inline int pcol(int i) {
    int j = i >> 1, odd = i & 1;
    return 32 * (j >> 4) + (j & 15) + 16 * odd;
}

// ---------- coarse histogram (LDS-privatized) ----------
__global__ __launch_bounds__(256) void chist(const int* __restrict__ coli, int E,
                                             int* __restrict__ ghist, int ncb) {
    __shared__ int h[NCB_MAX];
    for (int i = threadIdx.x; i < ncb; i += 256) h[i] = 0;
    __syncthreads();
    int e0 = blockIdx.x * EPB;
    int e1 = min(e0 + EPB, E);
    for (int e = e0 + threadIdx.x; e < e1; e += 256)
        atomicAdd(&h[coli[e] >> 8], 1);
    __syncthreads();
    for (int i = threadIdx.x; i < ncb; i += 256)
        if (h[i]) atomicAdd(&ghist[i], h[i]);
}

// ---------- 1-block scan of coarse histogram -> cstart, gcursor ----------
__global__ __launch_bounds__(NCB_MAX) void cscan(const int* __restrict__ ghist,
                                                 int* __restrict__ cstart,
                                                 int* __restrict__ gcursor,
                                                 int ncb, int E) {
    __shared__ int tmp[NCB_MAX];
    int tid = threadIdx.x;
    int v = (tid < ncb) ? ghist[tid] : 0;
    tmp[tid] = v;
    __syncthreads();
    for (int off = 1; off < NCB_MAX; off <<= 1) {
        int t = (tid >= off) ? tmp[tid - off] : 0;
        __syncthreads();
        tmp[tid] += t;
        __syncthreads();
    }
    if (tid < ncb) {
        int excl = tmp[tid] - v;
        cstart[tid] = excl;
        gcursor[tid] = excl;
    }
    if (tid == ncb - 1) cstart[ncb] = E;
}

// ---------- pass1: block-privatized scatter into coarse buckets ----------
// ebuf value = (row << 8) | (col & 255)   (requires N < 2^24)
__global__ __launch_bounds__(256) void pass1_scatter(const int* __restrict__ rowi,
                                                     const int* __restrict__ coli, int E,
                                                     int* __restrict__ gcursor,
                                                     unsigned* __restrict__ ebuf, int ncb) {
    __shared__ int hist[NCB_MAX];
    __shared__ int base[NCB_MAX];
    int e0 = blockIdx.x * EPB;
    int e1 = min(e0 + EPB, E);
    for (int i = threadIdx.x; i < ncb; i += 256) hist[i] = 0;
    __syncthreads();
    for (int e = e0 + threadIdx.x; e < e1; e += 256)
        atomicAdd(&hist[coli[e] >> 8], 1);
    __syncthreads();
    for (int i = threadIdx.x; i < ncb; i += 256) {
        int h = hist[i];
        base[i] = h ? atomicAdd(&gcursor[i], h) : 0;
        hist[i] = 0;
    }
    __syncthreads();
    for (int e = e0 + threadIdx.x; e < e1; e += 256) {
        int c = coli[e];
        int cb = c >> 8;
        int rank = atomicAdd(&hist[cb], 1);
        ebuf[base[cb] + rank] = ((unsigned)rowi[e] << 8) | (unsigned)(c & 255);
    }
}

// ---------- fused pass2: 1024-key counting sort by (node, src-bucket) ----------
// key = (local<<2) | srcbucket(row).  csr stays node-contiguous (node-major,
// bucket-minor); offsets2[node*4+b] gives per-bucket sublist boundaries.
__global__ __launch_bounds__(256) void pass2_all(const unsigned* __restrict__ ebuf,
                                                 const int* __restrict__ cstart,
                                                 int* __restrict__ offsets,
                                                 int* __restrict__ offsets2,
                                                 float* __restrict__ dinv,
                                                 int* __restrict__ csr_src,
                                                 int n, int E) {
    __shared__ int cnt[1024];
    __shared__ int kb[1024];
    __shared__ int scn[256];
    const int tid = threadIdx.x;
    const int cb = blockIdx.x;
#pragma unroll
    for (int j = 0; j < 4; j++) cnt[tid * 4 + j] = 0;
    __syncthreads();
    int s = cstart[cb], e1 = cstart[cb + 1];
    for (int e = s + tid; e < e1; e += 256) {
        unsigned u = ebuf[e];
        int key = ((u & 255u) << 2) | ((u >> 23) & 3u);
        atomicAdd(&cnt[key], 1);
    }
    __syncthreads();
    int c0 = cnt[tid * 4], c1 = cnt[tid * 4 + 1], c2 = cnt[tid * 4 + 2], c3 = cnt[tid * 4 + 3];
    int v = c0 + c1 + c2 + c3;
    scn[tid] = v;
    __syncthreads();
#pragma unroll
    for (int off = 1; off < 256; off <<= 1) {
        int t = (tid >= off) ? scn[tid - off] : 0;
        __syncthreads();
        scn[tid] += t;
        __syncthreads();
    }
    int base = s + scn[tid] - v;   // global exclusive offset for this node
    kb[tid * 4]     = base;
    kb[tid * 4 + 1] = base + c0;
    kb[tid * 4 + 2] = base + c0 + c1;
    kb[tid * 4 + 3] = base + c0 + c1 + c2;
    int node = (cb << 8) + tid;
    if (node < n) {
        offsets[node] = base;
        offsets2[node * 4]     = base;
        offsets2[node * 4 + 1] = base + c0;
        offsets2[node * 4 + 2] = base + c0 + c1;
        offsets2[node * 4 + 3] = base + c0 + c1 + c2;
        dinv[node] = rsqrtf((float)v + 1.0f);   // +1 = self loop
    }
    if (cb == 0 && tid == 0) { offsets[n] = E; offsets2[4 * n] = E; }
#pragma unroll
    for (int j = 0; j < 4; j++) cnt[tid * 4 + j] = 0;
    __syncthreads();
    for (int e = s + tid; e < e1; e += 256) {
        unsigned u = ebuf[e];
        int key = ((u & 255u) << 2) | ((u >> 23) & 3u);
        int rank = atomicAdd(&cnt[key], 1);
        csr_src[kb[key] + rank] = (int)(u >> 8);
    }
}

// ---------- weight prep (one dispatch): W1/Wg bf16 fragments + permuted b1/bg/Wfc ----------
__global__ __launch_bounds__(256) void wprep_all(const float* __restrict__ W1,
                                                 const float* __restrict__ b1,
                                                 const float* __restrict__ Wg,
                                                 const float* __restrict__ bg,
                                                 const float* __restrict__ Wfc,
                                                 uint4* __restrict__ wfrag,
                                                 float* __restrict__ b1p,
                                                 uint4* __restrict__ wg2frag,
                                                 float* __restrict__ bgp,
                                                 float2* __restrict__ wfcp) {
    int idx = blockIdx.x * 256 + threadIdx.x;
    if (idx < 3072) {
        int q = idx & 3, n = (idx >> 2) & 127, c = idx >> 9;
        int k0 = c * 32 + q * 8;
        float f[8];
#pragma unroll
        for (int j = 0; j < 8; j++) {
            int k = k0 + j;
            f[j] = (k < IN_DIM) ? W1[k * 128 + n] : 0.f;
        }
        uint4 u;
        u.x = pack_bf16(f[0], f[1]);
        u.y = pack_bf16(f[2], f[3]);
        u.z = pack_bf16(f[4], f[5]);
        u.w = pack_bf16(f[6], f[7]);
        wfrag[idx] = u;
    } else if (idx < 4096) {
        int i2 = idx - 3072;
        int q = i2 & 3, n = (i2 >> 2) & 63, c = i2 >> 8;
        float f[8];
#pragma unroll
        for (int j = 0; j < 8; j++) {
            int ks = c * 32 + q * 8 + j;
            f[j] = Wg[pcol(ks) * 64 + n];
        }
        uint4 u;
        u.x = pack_bf16(f[0], f[1]);
        u.y = pack_bf16(f[2], f[3]);
        u.z = pack_bf16(f[4], f[5]);
        u.w = pack_bf16(f[6], f[7]);
        wg2frag[i2] = u;
    }
    if (idx < 128) b1p[idx] = b1[pcol(idx)];
    if (idx < 64) {
        int o = pcol(idx);
        bgp[idx] = bg[o];
        wfcp[idx] = make_float2(Wfc[o * 2], Wfc[o * 2 + 1]);
    }
}

// ---------- GEMM1 via bf16 MFMA, LDS-free, x read directly (fused cvt) ----------
// Epilogue: int8 quantization, one f32 scale per row (h1s, L2-resident).
__global__ __launch_bounds__(256) void gemm1_mfma(const float* __restrict__ x,
                                                  const uint4* __restrict__ wfrag,
                                                  const float* __restrict__ dinv,
                                                  unsigned char* __restrict__ h1p8,
                                                  float* __restrict__ h1s, int M) {
    const int t = threadIdx.x;
    const int wave = t >> 6;
    const int lane = t & 63;
    const int l16 = lane & 15;
    const int quad = lane >> 4;
    const int rowbase = blockIdx.x * 64 + wave * 16;

    int arow = rowbase + l16;
    if (arow >= M) arow = M - 1;
    const float* xr = x + (size_t)arow * IN_DIM;

    f32x4 acc[8];
#pragma unroll
    for (int nt = 0; nt < 8; nt++) acc[nt] = (f32x4){0.f, 0.f, 0.f, 0.f};

#pragma unroll
    for (int c = 0; c < 6; c++) {
        int k0 = c * 32 + quad * 8;
        float f[8];
#pragma unroll
        for (int j = 0; j < 8; j++)
            f[j] = (k0 + j < IN_DIM) ? xr[k0 + j] : 0.f;
        uint4 au;
        au.x = pack_bf16(f[0], f[1]);
        au.y = pack_bf16(f[2], f[3]);
        au.z = pack_bf16(f[4], f[5]);
        au.w = pack_bf16(f[6], f[7]);
        bf16x8 a = __builtin_bit_cast(bf16x8, au);
#pragma unroll
        for (int nt = 0; nt < 8; nt++) {
            uint4 bu = wfrag[(size_t)((c * 128 + nt * 16 + l16) * 4 + quad)];
            bf16x8 b = __builtin_bit_cast(bf16x8, bu);
            acc[nt] = __builtin_amdgcn_mfma_f32_16x16x32_bf16(a, b, acc[nt], 0, 0, 0);
        }
    }

#pragma unroll
    for (int r = 0; r < 4; r++) {
        int row = rowbase + quad * 4 + r;
        if (row < M) {
            float s = dinv[row];
            float v[8];
#pragma unroll
            for (int nt = 0; nt < 8; nt++) v[nt] = acc[nt][r] * s;
            float gm = fabsf(v[0]);
#pragma unroll
            for (int nt = 1; nt < 8; nt++) gm = fmaxf(gm, fabsf(v[nt]));
            gm = fmaxf(gm, __shfl_xor(gm, 1, 16));
            gm = fmaxf(gm, __shfl_xor(gm, 2, 16));
            gm = fmaxf(gm, __shfl_xor(gm, 4, 16));
            gm = fmaxf(gm, __shfl_xor(gm, 8, 16));
            float inv = gm > 0.f ? 127.0f / gm : 0.f;
            unsigned short* hr = (unsigned short*)(h1p8 + (size_t)row * 128);
#pragma unroll
            for (int p = 0; p < 4; p++) {
                int q0 = (int)rintf(v[2 * p] * inv);
                int q1 = (int)rintf(v[2 * p + 1] * inv);
                hr[p * 16 + l16] = (unsigned short)((q0 & 0xff) | ((q1 & 0xff) << 8));
            }
            if (l16 == 0) h1s[row] = gm * (1.0f / 127.0f);
        }
    }
}

// 8 int8 -> f32, scaled accumulate (s = row scale)
__device__ inline void fma8i8(float* a, uint2 u, float s) {
    a[0] = fmaf((float)(char)(u.x), s, a[0]);
    a[1] = fmaf((float)(char)(u.x >> 8), s, a[1]);
    a[2] = fmaf((float)(char)(u.x >> 16), s, a[2]);
    a[3] = fmaf((float)(char)(u.x >> 24), s, a[3]);
    a[4] = fmaf((float)(char)(u.y), s, a[4]);
    a[5] = fmaf((float)(char)(u.y >> 8), s, a[5]);
    a[6] = fmaf((float)(char)(u.y >> 16), s, a[6]);
    a[7] = fmaf((float)(char)(u.y >> 24), s, a[7]);
}

__device__ inline void fma8(float* a, uint4 u, float w) {
    a[0] = fmaf(__uint_as_float(u.x << 16), w, a[0]);
    a[1] = fmaf(__uint_as_float(u.x & 0xFFFF0000u), w, a[1]);
    a[2] = fmaf(__uint_as_float(u.y << 16), w, a[2]);
    a[3] = fmaf(__uint_as_float(u.y & 0xFFFF0000u), w, a[3]);
    a[4] = fmaf(__uint_as_float(u.z << 16), w, a[4]);
    a[5] = fmaf(__uint_as_float(u.z & 0xFFFF0000u), w, a[5]);
    a[6] = fmaf(__uint_as_float(u.w << 16), w, a[6]);
    a[7] = fmaf(__uint_as_float(u.w & 0xFFFF0000u), w, a[7]);
}

__device__ inline float lexp(float e) {
    e = e > 0.f ? e : NSL * e;
    return __expf(e);
}

// ---------- GCN gather, src-range phased, 8-wide predicated sublists ----------
// Per (node,bucket) sublist ~Poisson(4) edges: one fully-unrolled 8-slot batch
// (inactive slots: clamped index, weight 0) issues ALL loads back-to-back ->
// ~8 rows in flight per group, no dependent-load serial tail (r5's killer).
// Grid 1024 = 4 blocks/CU co-resident; per-block __syncthreads per bucket
// keeps the 4 MiB source slab L2-resident per phase.
__global__ __launch_bounds__(256, 4) void gcn_gather(const int* __restrict__ offsets2,
                                                     const int* __restrict__ csr_src,
                                                     const uint2* __restrict__ h1v8,
                                                     const float* __restrict__ h1s,
                                                     const float* __restrict__ dinv,
                                                     const float* __restrict__ b1p,
                                                     uint4* __restrict__ gb,
                                                     int totq, int n) {
    int qid = (blockIdx.x << 4) + (threadIdx.x >> 4);
    int lane = threadIdx.x & 15;
    int nstart = (int)((long long)qid * n / totq);
    int nend   = (int)((long long)(qid + 1) * n / totq);

    float acc[NPQ][8];
#pragma unroll
    for (int i = 0; i < NPQ; i++)
#pragma unroll
        for (int j = 0; j < 8; j++) acc[i][j] = 0.f;

    for (int b = 0; b < NB; b++) {
#pragma unroll
        for (int i = 0; i < NPQ; i++) {
            int node = nstart + i;
            if (node < nend) {
                int k  = offsets2[(node << 2) | b];
                int e1 = offsets2[((node << 2) | b) + 1];
                while (k < e1) {
                    int m = e1 - k;                    // >= 1
                    int r[8];
#pragma unroll
                    for (int j = 0; j < 8; j++)
                        r[j] = csr_src[j < m ? k + j : k];
                    uint2 v[8];
#pragma unroll
                    for (int j = 0; j < 8; j++)
                        v[j] = h1v8[(size_t)r[j] * 16 + lane];
                    float w[8];
#pragma unroll
                    for (int j = 0; j < 8; j++)
                        w[j] = (j < m) ? h1s[r[j]] : 0.f;
#pragma unroll
                    for (int j = 0; j < 8; j++)
                        fma8i8(acc[i], v[j], w[j]);
                    k += 8;
                }
            }
        }
        __syncthreads();
    }

#pragma unroll
    for (int i = 0; i < NPQ; i++) {
        int node = nstart + i;
        if (node < nend) {
            fma8i8(acc[i], h1v8[(size_t)node * 16 + lane], h1s[node]);   // self loop
            float dc = dinv[node];
            float4 bb0 = ((const float4*)b1p)[lane * 2];
            float4 bb1 = ((const float4*)b1p)[lane * 2 + 1];
            float o[8];
            o[0] = fmaxf(acc[i][0] * dc + bb0.x, 0.f);
            o[1] = fmaxf(acc[i][1] * dc + bb0.y, 0.f);
            o[2] = fmaxf(acc[i][2] * dc + bb0.z, 0.f);
            o[3] = fmaxf(acc[i][3] * dc + bb0.w, 0.f);
            o[4] = fmaxf(acc[i][4] * dc + bb1.x, 0.f);
            o[5] = fmaxf(acc[i][5] * dc + bb1.y, 0.f);
            o[6] = fmaxf(acc[i][6] * dc + bb1.z, 0.f);
            o[7] = fmaxf(acc[i][7] * dc + bb1.w, 0.f);
            uint4 pk;
            pk.x = pack_bf16(o[0], o[1]);
            pk.y = pack_bf16(o[2], o[3]);
            pk.z = pack_bf16(o[4], o[5]);
            pk.w = pack_bf16(o[6], o[7]);
            gb[(size_t)node * 16 + lane] = pk;
        }
    }
}

// ---------- GEMM2 via bf16 MFMA, LDS-free; fused es/ed; bf16 h2 out ----------
__global__ __launch_bounds__(256) void gemm2_mfma(const uint4* __restrict__ gb4,
                                                  const uint4* __restrict__ wg2frag,
                                                  const float* __restrict__ a_src,
                                                  const float* __restrict__ a_dst,
                                                  unsigned* __restrict__ h2b,
                                                  float* __restrict__ es,
                                                  float* __restrict__ ed, int M) {
    const int t = threadIdx.x;
    const int wave = t >> 6;
    const int lane = t & 63;
    const int l16 = lane & 15;
    const int quad = lane >> 4;
    const int rowbase = blockIdx.x * 64 + wave * 16;

    int arow = rowbase + l16;
    if (arow >= M) arow = M - 1;

    f32x4 acc[4];
#pragma unroll
    for (int nt = 0; nt < 4; nt++) acc[nt] = (f32x4){0.f, 0.f, 0.f, 0.f};

#pragma unroll
    for (int c = 0; c < 4; c++) {
        uint4 au = gb4[(size_t)arow * 16 + c * 4 + quad];
        bf16x8 a = __builtin_bit_cast(bf16x8, au);
#pragma unroll
        for (int nt = 0; nt < 4; nt++) {
            uint4 bu = wg2frag[(size_t)((c * 64 + nt * 16 + l16) * 4 + quad)];
            bf16x8 b = __builtin_bit_cast(bf16x8, bu);
            acc[nt] = __builtin_amdgcn_mfma_f32_16x16x32_bf16(a, b, acc[nt], 0, 0, 0);
        }
    }

    float as0 = a_src[l16], as1 = a_src[16 + l16], as2 = a_src[32 + l16], as3 = a_src[48 + l16];
    float ad0 = a_dst[l16], ad1 = a_dst[16 + l16], ad2 = a_dst[32 + l16], ad3 = a_dst[48 + l16];

#pragma unroll
    for (int r = 0; r < 4; r++) {
        int row = rowbase + quad * 4 + r;
        float ps = acc[0][r] * as0 + acc[1][r] * as1 + acc[2][r] * as2 + acc[3][r] * as3;
        float pd = acc[0][r] * ad0 + acc[1][r] * ad1 + acc[2][r] * ad2 + acc[3][r] * ad3;
#pragma unroll
        for (int m = 8; m; m >>= 1) {
            ps += __shfl_xor(ps, m, 16);
            pd += __shfl_xor(pd, m, 16);
        }
        if (row < M) {
            h2b[(size_t)row * 32 + l16]      = pack_bf16(acc[0][r], acc[1][r]);
            h2b[(size_t)row * 32 + 16 + l16] = pack_bf16(acc[2][r], acc[3][r]);
            if (l16 == 0) { es[row] = ps; ed[row] = pd; }
        }
    }
}

// ---------- fused GAT, src-range phased, 8-wide predicated sublists ----------
__global__ __launch_bounds__(256, 4) void gat_fused(const int* __restrict__ offsets2,
                                                    const int* __restrict__ csr_src,
                                                    const uint4* __restrict__ h2v,  // row = 8 uint4
                                                    const float* __restrict__ es,
                                                    const float* __restrict__ ed,
                                                    const float* __restrict__ bgp,
                                                    const float2* __restrict__ wfcp,
                                                    const float* __restrict__ bfc,
                                                    float* __restrict__ out,
                                                    int totq, int n) {
    int qid = (blockIdx.x << 5) + (threadIdx.x >> 3);
    int lane = threadIdx.x & 7;
    int nstart = (int)((long long)qid * n / totq);
    int nend   = (int)((long long)(qid + 1) * n / totq);

    float acc[NPG][8];
    float ssum[NPG];
    float edc[NPG];
#pragma unroll
    for (int i = 0; i < NPG; i++) {
        ssum[i] = 0.f;
        int node = nstart + i;
        edc[i] = (node < nend) ? ed[node] : 0.f;
#pragma unroll
        for (int j = 0; j < 8; j++) acc[i][j] = 0.f;
    }

    for (int b = 0; b < NB; b++) {
#pragma unroll
        for (int i = 0; i < NPG; i++) {
            int node = nstart + i;
            if (node < nend) {
                int k  = offsets2[(node << 2) | b];
                int e1 = offsets2[((node << 2) | b) + 1];
                float ec = edc[i];
                while (k < e1) {
                    int m = e1 - k;
                    int r[8];
#pragma unroll
                    for (int j = 0; j < 8; j++)
                        r[j] = csr_src[j < m ? k + j : k];
                    float ev[8];
#pragma unroll
                    for (int j = 0; j < 8; j++)
                        ev[j] = es[r[j]];
                    uint4 v[8];
#pragma unroll
                    for (int j = 0; j < 8; j++)
                        v[j] = h2v[(size_t)r[j] * 8 + lane];
                    float xs = 0.f;
#pragma unroll
                    for (int j = 0; j < 8; j++) {
                        float xv = (j < m) ? lexp(ev[j] + ec) : 0.f;
                        xs += xv;
                        fma8(acc[i], v[j], xv);
                    }
                    ssum[i] += xs;
                    k += 8;
                }
            }
        }
        __syncthreads();
    }

#pragma unroll
    for (int i = 0; i < NPG; i++) {
        int node = nstart + i;
        if (node < nend) {
            float x0s = lexp(es[node] + edc[i]);          // self loop
            fma8(acc[i], h2v[(size_t)node * 8 + lane], x0s);
            float rcp = 1.0f / (ssum[i] + x0s);
            float4 b0 = ((const float4*)bgp)[lane * 2];
            float4 b1 = ((const float4*)bgp)[lane * 2 + 1];
            float o[8];
            o[0] = fmaxf(acc[i][0] * rcp + b0.x, 0.f);
            o[1] = fmaxf(acc[i][1] * rcp + b0.y, 0.f);
            o[2] = fmaxf(acc[i][2] * rcp + b0.z, 0.f);
            o[3] = fmaxf(acc[i][3] * rcp + b0.w, 0.f);
            o[4] = fmaxf(acc[i][4] * rcp + b1.x, 0.f);
            o[5] = fmaxf(acc[i][5] * rcp + b1.y, 0.f);
            o[6] = fmaxf(acc[i][6] * rcp + b1.z, 0.f);
            o[7] = fmaxf(acc[i][7] * rcp + b1.w, 0.f);

            float p0 = 0.f, p1 = 0.f;
#pragma unroll
            for (int m2 = 0; m2 < 4; m2++) {
                float4 w = ((const float4*)wfcp)[lane * 4 + m2];
                p0 += o[2 * m2] * w.x + o[2 * m2 + 1] * w.z;
                p1 += o[2 * m2] * w.y + o[2 * m2 + 1] * w.w;
            }
#pragma unroll
            for (int m = 4; m; m >>= 1) {
                p0 += __shfl_xor(p0, m, 8);
                p1 += __shfl_xor(p1, m, 8);
            }
            if (lane == 0) {
                out[(size_t)node * 2 + 0] = p0 + bfc[0];
                out[(size_t)node * 2 + 1] = p1 + bfc[1];
            }
        }
    }
}

extern "C" void kernel_launch(void* const* d_in, const int* in_sizes, int n_in,
                              void* d_out, int out_size, void* d_ws, size_t ws_size,
                              hipStream_t stream) {
    const float* x     = (const float*)d_in[0];
    const int*   ei    = (const int*)d_in[1];
    const float* W1    = (const float*)d_in[2];
    const float* b1    = (const float*)d_in[3];
    const float* Wg    = (const float*)d_in[4];
    const float* a_src = (const float*)d_in[5];
    const float* a_dst = (const float*)d_in[6];
    const float* bg    = (const float*)d_in[7];
    const float* Wfc   = (const float*)d_in[8];
    const float* bfc   = (const float*)d_in[9];
    float* out = (float*)d_out;

    const int N = in_sizes[0] / IN_DIM;
    const int E = in_sizes[1] / 2;
    const int* rowi = ei;
    const int* coli = ei + E;
    const int ncb = (N + 255) >> 8;            // coarse buckets of 256 nodes

    auto alignup = [](char* p) { return (char*)(((uintptr_t)p + 15) & ~(uintptr_t)15); };

    // workspace layout
    char* wsb = (char*)d_ws;
    int*   offsets  = (int*)wsb;                        // N+8
    int*   offsets2 = offsets + N + 8;                  // 4N+8 (per src-bucket)
    float* dinv    = (float*)(offsets2 + 4 * N + 8);    // N
    float* es      = dinv + N;                          // N
    float* ed      = es + N;                            // N
    float* h1s     = ed + N;                            // N (f32 row scales, 400 KB)
    int*   ghist   = (int*)(h1s + N);                   // NCB_MAX
    int*   cstart  = ghist + NCB_MAX;                   // NCB_MAX+2
    int*   gcursor = cstart + NCB_MAX + 2;              // NCB_MAX
    float* b1p     = (float*)(gcursor + NCB_MAX);       // 128
    float* bgp     = b1p + 128;                         // 64
    float2* wfcp   = (float2*)(bgp + 64);               // 64 float2
    uint4* wfrag   = (uint4*)alignup((char*)(wfcp + 64));   // 3072 uint4 (48 KB)
    uint4* wg2frag = wfrag + 3072;                      // 1024 uint4 (16 KB)
    int*   csr_src = (int*)(wg2frag + 1024);            // E
    unsigned* ebuf = (unsigned*)(csr_src + E);          // E (packed row<<8|local)
    unsigned char* h1p8 = (unsigned char*)alignup((char*)(ebuf + E)); // N*128 bytes (int8, perm)
    uint4* gb      = (uint4*)alignup((char*)(h1p8 + (size_t)N * 128)); // N*16 uint4
    unsigned* h2b  = (unsigned*)h1p8;  // alias: h1p8 dead after gcn_gather; h2b = N*32 words

    hipMemsetAsync(ghist, 0, NCB_MAX * 4, stream);

    const int nbE = (E + EPB - 1) / EPB;

    // 1) CSR build: coarse hist -> scan -> privatized scatter -> fused fine sort
    chist<<<nbE, 256, 0, stream>>>(coli, E, ghist, ncb);
    cscan<<<1, NCB_MAX, 0, stream>>>(ghist, cstart, gcursor, ncb, E);
    pass1_scatter<<<nbE, 256, 0, stream>>>(rowi, coli, E, gcursor, ebuf, ncb);
    pass2_all<<<ncb, 256, 0, stream>>>(ebuf, cstart, offsets, offsets2, dinv, csr_src, N, E);

    // 2) weight prep (single dispatch)
    wprep_all<<<16, 256, 0, stream>>>(W1, b1, Wg, bg, Wfc, wfrag, b1p, wg2frag, bgp, wfcp);

    // 3) h1p8 = int8-row-quant((x @ W1) * dinv[row]) via LDS-free MFMA
    gemm1_mfma<<<(N + 63) / 64, 256, 0, stream>>>(x, wfrag, dinv, h1p8, h1s, N);

    // 4) GCN gather, phased over 4 source ranges (co-resident grid, 4 blocks/CU)
    int gblocks = 1024;
    while ((long long)gblocks * 16 * NPQ < (long long)N) gblocks += 256;
    gcn_gather<<<gblocks, 256, 0, stream>>>(offsets2, csr_src, (const uint2*)h1p8,
                                            h1s, dinv, b1p, gb, gblocks * 16, N);

    // 5) h2b = bf16(g @ Wg) via LDS-free MFMA, fused es/ed epilogue
    gemm2_mfma<<<(N + 63) / 64, 256, 0, stream>>>(gb, wg2frag, a_src, a_dst, h2b, es, ed, N);

    // 6) fused GAT, phased over 4 source ranges
    int ablocks = 1024;
    while ((long long)ablocks * 32 * NPG < (long long)N) ablocks += 256;
    gat_fused<<<ablocks, 256, 0, stream>>>(offsets2, csr_src, (const uint4*)h2b,
                                           es, ed, bgp, wfcp, bfc, out, ablocks * 32, N);
}

// Round 7
// 324.328 us; speedup vs baseline: 1.2264x; 1.0963x over previous
//
#include <hip/hip_runtime.h>
#include <math.h>

#define NSL 0.2f   // leaky relu negative slope
#define IN_DIM 165
#define HID 128
#define OUT_H 64
#define NCB_MAX 512 // max coarse buckets (N <= 131072)
#define EPB 4096    // edges per pass1 block

typedef __attribute__((ext_vector_type(8))) short bf16x8;
typedef __attribute__((ext_vector_type(4))) float f32x4;

// ---------- bf16 pack (round-to-nearest-even) ----------
__device__ inline unsigned pack_bf16(float a, float b) {
    unsigned ua = __float_as_uint(a);
    ua += 0x7FFFu + ((ua >> 16) & 1u);
    unsigned ub = __float_as_uint(b);
    ub += 0x7FFFu + ((ub >> 16) & 1u);
    return (ua >> 16) | (ub & 0xFFFF0000u);
}

// column permutation of the packed layouts: stored bf16 index i -> original col.
__device__ __host__ inline int pcol(int i) {
    int j = i >> 1, odd = i & 1;
    return 32 * (j >> 4) + (j & 15) + 16 * odd;
}

// ---------- coarse histogram (LDS-privatized) ----------
__global__ __launch_bounds__(256) void chist(const int* __restrict__ coli, int E,
                                             int* __restrict__ ghist, int ncb) {
    __shared__ int h[NCB_MAX];
    for (int i = threadIdx.x; i < ncb; i += 256) h[i] = 0;
    __syncthreads();
    int e0 = blockIdx.x * EPB;
    int e1 = min(e0 + EPB, E);
    for (int e = e0 + threadIdx.x; e < e1; e += 256)
        atomicAdd(&h[coli[e] >> 8], 1);
    __syncthreads();
    for (int i = threadIdx.x; i < ncb; i += 256)
        if (h[i]) atomicAdd(&ghist[i], h[i]);
}

// ---------- 1-block scan of coarse histogram -> cstart, gcursor ----------
__global__ __launch_bounds__(NCB_MAX) void cscan(const int* __restrict__ ghist,
                                                 int* __restrict__ cstart,
                                                 int* __restrict__ gcursor,
                                                 int ncb, int E) {
    __shared__ int tmp[NCB_MAX];
    int tid = threadIdx.x;
    int v = (tid < ncb) ? ghist[tid] : 0;
    tmp[tid] = v;
    __syncthreads();
    for (int off = 1; off < NCB_MAX; off <<= 1) {
        int t = (tid >= off) ? tmp[tid - off] : 0;
        __syncthreads();
        tmp[tid] += t;
        __syncthreads();
    }
    if (tid < ncb) {
        int excl = tmp[tid] - v;
        cstart[tid] = excl;
        gcursor[tid] = excl;
    }
    if (tid == ncb - 1) cstart[ncb] = E;
}

// ---------- pass1: block-privatized scatter into coarse buckets ----------
// ebuf value = (row << 8) | (col & 255)   (requires N < 2^24)
__global__ __launch_bounds__(256) void pass1_scatter(const int* __restrict__ rowi,
                                                     const int* __restrict__ coli, int E,
                                                     int* __restrict__ gcursor,
                                                     unsigned* __restrict__ ebuf, int ncb) {
    __shared__ int hist[NCB_MAX];
    __shared__ int base[NCB_MAX];
    int e0 = blockIdx.x * EPB;
    int e1 = min(e0 + EPB, E);
    for (int i = threadIdx.x; i < ncb; i += 256) hist[i] = 0;
    __syncthreads();
    for (int e = e0 + threadIdx.x; e < e1; e += 256)
        atomicAdd(&hist[coli[e] >> 8], 1);
    __syncthreads();
    for (int i = threadIdx.x; i < ncb; i += 256) {
        int h = hist[i];
        base[i] = h ? atomicAdd(&gcursor[i], h) : 0;
        hist[i] = 0;
    }
    __syncthreads();
    for (int e = e0 + threadIdx.x; e < e1; e += 256) {
        int c = coli[e];
        int cb = c >> 8;
        int rank = atomicAdd(&hist[cb], 1);
        ebuf[base[cb] + rank] = ((unsigned)rowi[e] << 8) | (unsigned)(c & 255);
    }
}

// ---------- fused pass2: count -> local scan -> offsets/dinv -> rank+fill ----------
__global__ __launch_bounds__(256) void pass2_all(const unsigned* __restrict__ ebuf,
                                                 const int* __restrict__ cstart,
                                                 int* __restrict__ offsets,
                                                 float* __restrict__ dinv,
                                                 int* __restrict__ csr_src,
                                                 int n, int E) {
    __shared__ int cnt[256];
    __shared__ int scan[256];
    __shared__ int offs[256];
    const int tid = threadIdx.x;
    const int cb = blockIdx.x;
    cnt[tid] = 0;
    __syncthreads();
    int s = cstart[cb], e1 = cstart[cb + 1];
    for (int e = s + tid; e < e1; e += 256)
        atomicAdd(&cnt[ebuf[e] & 255u], 1);
    __syncthreads();
    int v = cnt[tid];
    scan[tid] = v;
    __syncthreads();
#pragma unroll
    for (int off = 1; off < 256; off <<= 1) {
        int t = (tid >= off) ? scan[tid - off] : 0;
        __syncthreads();
        scan[tid] += t;
        __syncthreads();
    }
    int off0 = s + scan[tid] - v;   // global exclusive offset for this node
    offs[tid] = off0;
    int node = (cb << 8) + tid;
    if (node < n) {
        offsets[node] = off0;
        dinv[node] = rsqrtf((float)v + 1.0f);   // +1 = self loop
    }
    if (cb == 0 && tid == 0) offsets[n] = E;
    cnt[tid] = 0;
    __syncthreads();
    for (int e = s + tid; e < e1; e += 256) {
        unsigned u = ebuf[e];
        int local = u & 255u;
        int rank = atomicAdd(&cnt[local], 1);
        csr_src[offs[local] + rank] = (int)(u >> 8);
    }
}

// ---------- weight prep (one dispatch): W1/Wg bf16 fragments + permuted b1/bg/Wfc ----------
__global__ __launch_bounds__(256) void wprep_all(const float* __restrict__ W1,
                                                 const float* __restrict__ b1,
                                                 const float* __restrict__ Wg,
                                                 const float* __restrict__ bg,
                                                 const float* __restrict__ Wfc,
                                                 uint4* __restrict__ wfrag,
                                                 float* __restrict__ b1p,
                                                 uint4* __restrict__ wg2frag,
                                                 float* __restrict__ bgp,
                                                 float2* __restrict__ wfcp) {
    int idx = blockIdx.x * 256 + threadIdx.x;
    if (idx < 3072) {
        int q = idx & 3, n = (idx >> 2) & 127, c = idx >> 9;
        int k0 = c * 32 + q * 8;
        float f[8];
#pragma unroll
        for (int j = 0; j < 8; j++) {
            int k = k0 + j;
            f[j] = (k < IN_DIM) ? W1[k * 128 + n] : 0.f;
        }
        uint4 u;
        u.x = pack_bf16(f[0], f[1]);
        u.y = pack_bf16(f[2], f[3]);
        u.z = pack_bf16(f[4], f[5]);
        u.w = pack_bf16(f[6], f[7]);
        wfrag[idx] = u;
    } else if (idx < 4096) {
        int i2 = idx - 3072;
        int q = i2 & 3, n = (i2 >> 2) & 63, c = i2 >> 8;
        float f[8];
#pragma unroll
        for (int j = 0; j < 8; j++) {
            int ks = c * 32 + q * 8 + j;
            f[j] = Wg[pcol(ks) * 64 + n];
        }
        uint4 u;
        u.x = pack_bf16(f[0], f[1]);
        u.y = pack_bf16(f[2], f[3]);
        u.z = pack_bf16(f[4], f[5]);
        u.w = pack_bf16(f[6], f[7]);
        wg2frag[i2] = u;
    }
    if (idx < 128) b1p[idx] = b1[pcol(idx)];
    if (idx < 64) {
        int o = pcol(idx);
        bgp[idx] = bg[o];
        wfcp[idx] = make_float2(Wfc[o * 2], Wfc[o * 2 + 1]);
    }
}

// ---------- GEMM1 via bf16 MFMA, LDS-free, x read directly (fused cvt) ----------
// Epilogue: int8 quantization, one f32 scale per row (h1s, L2-resident).
__global__ __launch_bounds__(256) void gemm1_mfma(const float* __restrict__ x,
                                                  const uint4* __restrict__ wfrag,
                                                  const float* __restrict__ dinv,
                                                  unsigned char* __restrict__ h1p8,
                                                  float* __restrict__ h1s, int M) {
    const int t = threadIdx.x;
    const int wave = t >> 6;
    const int lane = t & 63;
    const int l16 = lane & 15;
    const int quad = lane >> 4;
    const int rowbase = blockIdx.x * 64 + wave * 16;

    int arow = rowbase + l16;
    if (arow >= M) arow = M - 1;
    const float* xr = x + (size_t)arow * IN_DIM;

    f32x4 acc[8];
#pragma unroll
    for (int nt = 0; nt < 8; nt++) acc[nt] = (f32x4){0.f, 0.f, 0.f, 0.f};

#pragma unroll
    for (int c = 0; c < 6; c++) {
        int k0 = c * 32 + quad * 8;
        float f[8];
#pragma unroll
        for (int j = 0; j < 8; j++)
            f[j] = (k0 + j < IN_DIM) ? xr[k0 + j] : 0.f;
        uint4 au;
        au.x = pack_bf16(f[0], f[1]);
        au.y = pack_bf16(f[2], f[3]);
        au.z = pack_bf16(f[4], f[5]);
        au.w = pack_bf16(f[6], f[7]);
        bf16x8 a = __builtin_bit_cast(bf16x8, au);
#pragma unroll
        for (int nt = 0; nt < 8; nt++) {
            uint4 bu = wfrag[(size_t)((c * 128 + nt * 16 + l16) * 4 + quad)];
            bf16x8 b = __builtin_bit_cast(bf16x8, bu);
            acc[nt] = __builtin_amdgcn_mfma_f32_16x16x32_bf16(a, b, acc[nt], 0, 0, 0);
        }
    }

#pragma unroll
    for (int r = 0; r < 4; r++) {
        int row = rowbase + quad * 4 + r;
        if (row < M) {
            float s = dinv[row];
            float v[8];
#pragma unroll
            for (int nt = 0; nt < 8; nt++) v[nt] = acc[nt][r] * s;
            float gm = fabsf(v[0]);
#pragma unroll
            for (int nt = 1; nt < 8; nt++) gm = fmaxf(gm, fabsf(v[nt]));
            gm = fmaxf(gm, __shfl_xor(gm, 1, 16));
            gm = fmaxf(gm, __shfl_xor(gm, 2, 16));
            gm = fmaxf(gm, __shfl_xor(gm, 4, 16));
            gm = fmaxf(gm, __shfl_xor(gm, 8, 16));
            float inv = gm > 0.f ? 127.0f / gm : 0.f;
            unsigned short* hr = (unsigned short*)(h1p8 + (size_t)row * 128);
#pragma unroll
            for (int p = 0; p < 4; p++) {
                int q0 = (int)rintf(v[2 * p] * inv);
                int q1 = (int)rintf(v[2 * p + 1] * inv);
                hr[p * 16 + l16] = (unsigned short)((q0 & 0xff) | ((q1 & 0xff) << 8));
            }
            if (l16 == 0) h1s[row] = gm * (1.0f / 127.0f);
        }
    }
}

// 8 int8 -> f32, scaled accumulate (s = row scale)
__device__ inline void fma8i8(float* a, uint2 u, float s) {
    a[0] = fmaf((float)(char)(u.x), s, a[0]);
    a[1] = fmaf((float)(char)(u.x >> 8), s, a[1]);
    a[2] = fmaf((float)(char)(u.x >> 16), s, a[2]);
    a[3] = fmaf((float)(char)(u.x >> 24), s, a[3]);
    a[4] = fmaf((float)(char)(u.y), s, a[4]);
    a[5] = fmaf((float)(char)(u.y >> 8), s, a[5]);
    a[6] = fmaf((float)(char)(u.y >> 16), s, a[6]);
    a[7] = fmaf((float)(char)(u.y >> 24), s, a[7]);
}

__device__ inline void fma8(float* a, uint4 u, float w) {
    a[0] = fmaf(__uint_as_float(u.x << 16), w, a[0]);
    a[1] = fmaf(__uint_as_float(u.x & 0xFFFF0000u), w, a[1]);
    a[2] = fmaf(__uint_as_float(u.y << 16), w, a[2]);
    a[3] = fmaf(__uint_as_float(u.y & 0xFFFF0000u), w, a[3]);
    a[4] = fmaf(__uint_as_float(u.z << 16), w, a[4]);
    a[5] = fmaf(__uint_as_float(u.z & 0xFFFF0000u), w, a[5]);
    a[6] = fmaf(__uint_as_float(u.w << 16), w, a[6]);
    a[7] = fmaf(__uint_as_float(u.w & 0xFFFF0000u), w, a[7]);
}

__device__ inline float lexp(float e) {
    e = e > 0.f ? e : NSL * e;
    return __expf(e);
}

// ---------- GCN gather: quarter-wave per dst node, int8+row-scale, deep pipeline ----------
// r4 structure (unphased, 46% occupancy) but with DOUBLE-BUFFERED 8-WIDE batches:
// 16 row-fetches (2 KB/group) in flight in steady state (r4 had 8/1 KB, rate
// 3.23 of 3.69 TB/s ceiling). Tail (<8 edges) is one predicated 8-batch that
// issues all loads at once (no dependent serial chain).
__global__ __launch_bounds__(256) void gcn_gather(const int* __restrict__ offsets,
                                                  const int* __restrict__ csr_src,
                                                  const uint2* __restrict__ h1v8,
                                                  const float* __restrict__ h1s,
                                                  const float* __restrict__ dinv,
                                                  const float* __restrict__ b1p,
                                                  uint4* __restrict__ gb, int n) {
    int node = (blockIdx.x * 256 + threadIdx.x) >> 4;
    int lane = threadIdx.x & 15;
    if (node >= n) return;
    int s0 = offsets[node], s1 = offsets[node + 1];

    float a0[8], a1[8], a2[8], a3[8];
#pragma unroll
    for (int i = 0; i < 8; i++) { a0[i] = 0.f; a1[i] = 0.f; a2[i] = 0.f; a3[i] = 0.f; }
    fma8i8(a0, h1v8[(size_t)node * 16 + lane], h1s[node]);   // self loop

    int k = s0;
    if (s1 - k >= 8) {
        uint2 vA[8];
        float wA[8];
        {
            int r[8];
#pragma unroll
            for (int j = 0; j < 8; j++) r[j] = csr_src[k + j];
#pragma unroll
            for (int j = 0; j < 8; j++) vA[j] = h1v8[(size_t)r[j] * 16 + lane];
#pragma unroll
            for (int j = 0; j < 8; j++) wA[j] = h1s[r[j]];
        }
        k += 8;
        while (s1 - k >= 8) {
            uint2 vB[8];
            float wB[8];
            {
                int r[8];
#pragma unroll
                for (int j = 0; j < 8; j++) r[j] = csr_src[k + j];
#pragma unroll
                for (int j = 0; j < 8; j++) vB[j] = h1v8[(size_t)r[j] * 16 + lane];
#pragma unroll
                for (int j = 0; j < 8; j++) wB[j] = h1s[r[j]];
            }
            k += 8;
            fma8i8(a0, vA[0], wA[0]);
            fma8i8(a1, vA[1], wA[1]);
            fma8i8(a2, vA[2], wA[2]);
            fma8i8(a3, vA[3], wA[3]);
            fma8i8(a0, vA[4], wA[4]);
            fma8i8(a1, vA[5], wA[5]);
            fma8i8(a2, vA[6], wA[6]);
            fma8i8(a3, vA[7], wA[7]);
#pragma unroll
            for (int j = 0; j < 8; j++) { vA[j] = vB[j]; wA[j] = wB[j]; }
        }
        fma8i8(a0, vA[0], wA[0]);
        fma8i8(a1, vA[1], wA[1]);
        fma8i8(a2, vA[2], wA[2]);
        fma8i8(a3, vA[3], wA[3]);
        fma8i8(a0, vA[4], wA[4]);
        fma8i8(a1, vA[5], wA[5]);
        fma8i8(a2, vA[6], wA[6]);
        fma8i8(a3, vA[7], wA[7]);
    }
    int m = s1 - k;
    if (m > 0) {
        // predicated tail batch: all loads issued back-to-back, weight 0 for pads
        int r[8];
#pragma unroll
        for (int j = 0; j < 8; j++) r[j] = csr_src[j < m ? k + j : k];
        uint2 v[8];
#pragma unroll
        for (int j = 0; j < 8; j++) v[j] = h1v8[(size_t)r[j] * 16 + lane];
        float w[8];
#pragma unroll
        for (int j = 0; j < 8; j++) w[j] = (j < m) ? h1s[r[j]] : 0.f;
        fma8i8(a0, v[0], w[0]);
        fma8i8(a1, v[1], w[1]);
        fma8i8(a2, v[2], w[2]);
        fma8i8(a3, v[3], w[3]);
        fma8i8(a0, v[4], w[4]);
        fma8i8(a1, v[5], w[5]);
        fma8i8(a2, v[6], w[6]);
        fma8i8(a3, v[7], w[7]);
    }

    float dc = dinv[node];
    float4 bb0 = ((const float4*)b1p)[lane * 2];
    float4 bb1 = ((const float4*)b1p)[lane * 2 + 1];
    float o[8];
    o[0] = fmaxf(((a0[0] + a1[0]) + (a2[0] + a3[0])) * dc + bb0.x, 0.f);
    o[1] = fmaxf(((a0[1] + a1[1]) + (a2[1] + a3[1])) * dc + bb0.y, 0.f);
    o[2] = fmaxf(((a0[2] + a1[2]) + (a2[2] + a3[2])) * dc + bb0.z, 0.f);
    o[3] = fmaxf(((a0[3] + a1[3]) + (a2[3] + a3[3])) * dc + bb0.w, 0.f);
    o[4] = fmaxf(((a0[4] + a1[4]) + (a2[4] + a3[4])) * dc + bb1.x, 0.f);
    o[5] = fmaxf(((a0[5] + a1[5]) + (a2[5] + a3[5])) * dc + bb1.y, 0.f);
    o[6] = fmaxf(((a0[6] + a1[6]) + (a2[6] + a3[6])) * dc + bb1.z, 0.f);
    o[7] = fmaxf(((a0[7] + a1[7]) + (a2[7] + a3[7])) * dc + bb1.w, 0.f);
    uint4 pk;
    pk.x = pack_bf16(o[0], o[1]);
    pk.y = pack_bf16(o[2], o[3]);
    pk.z = pack_bf16(o[4], o[5]);
    pk.w = pack_bf16(o[6], o[7]);
    gb[(size_t)node * 16 + lane] = pk;
}

// ---------- GEMM2 via bf16 MFMA, LDS-free; fused es/ed; bf16 h2 out ----------
__global__ __launch_bounds__(256) void gemm2_mfma(const uint4* __restrict__ gb4,
                                                  const uint4* __restrict__ wg2frag,
                                                  const float* __restrict__ a_src,
                                                  const float* __restrict__ a_dst,
                                                  unsigned* __restrict__ h2b,
                                                  float* __restrict__ es,
                                                  float* __restrict__ ed, int M) {
    const int t = threadIdx.x;
    const int wave = t >> 6;
    const int lane = t & 63;
    const int l16 = lane & 15;
    const int quad = lane >> 4;
    const int rowbase = blockIdx.x * 64 + wave * 16;

    int arow = rowbase + l16;
    if (arow >= M) arow = M - 1;

    f32x4 acc[4];
#pragma unroll
    for (int nt = 0; nt < 4; nt++) acc[nt] = (f32x4){0.f, 0.f, 0.f, 0.f};

#pragma unroll
    for (int c = 0; c < 4; c++) {
        uint4 au = gb4[(size_t)arow * 16 + c * 4 + quad];
        bf16x8 a = __builtin_bit_cast(bf16x8, au);
#pragma unroll
        for (int nt = 0; nt < 4; nt++) {
            uint4 bu = wg2frag[(size_t)((c * 64 + nt * 16 + l16) * 4 + quad)];
            bf16x8 b = __builtin_bit_cast(bf16x8, bu);
            acc[nt] = __builtin_amdgcn_mfma_f32_16x16x32_bf16(a, b, acc[nt], 0, 0, 0);
        }
    }

    float as0 = a_src[l16], as1 = a_src[16 + l16], as2 = a_src[32 + l16], as3 = a_src[48 + l16];
    float ad0 = a_dst[l16], ad1 = a_dst[16 + l16], ad2 = a_dst[32 + l16], ad3 = a_dst[48 + l16];

#pragma unroll
    for (int r = 0; r < 4; r++) {
        int row = rowbase + quad * 4 + r;
        float ps = acc[0][r] * as0 + acc[1][r] * as1 + acc[2][r] * as2 + acc[3][r] * as3;
        float pd = acc[0][r] * ad0 + acc[1][r] * ad1 + acc[2][r] * ad2 + acc[3][r] * ad3;
#pragma unroll
        for (int m = 8; m; m >>= 1) {
            ps += __shfl_xor(ps, m, 16);
            pd += __shfl_xor(pd, m, 16);
        }
        if (row < M) {
            h2b[(size_t)row * 32 + l16]      = pack_bf16(acc[0][r], acc[1][r]);
            h2b[(size_t)row * 32 + 16 + l16] = pack_bf16(acc[2][r], acc[3][r]);
            if (l16 == 0) { es[row] = ps; ed[row] = pd; }
        }
    }
}

// ---------- fused GAT: 8 lanes per node, bf16 h2 rows, unnormalized softmax ----------
__global__ __launch_bounds__(256) void gat_fused(const int* __restrict__ offsets,
                                                 const int* __restrict__ csr_src,
                                                 const uint4* __restrict__ h2v,  // row = 8 uint4
                                                 const float* __restrict__ es,
                                                 const float* __restrict__ ed,
                                                 const float* __restrict__ bgp,
                                                 const float2* __restrict__ wfcp,
                                                 const float* __restrict__ bfc,
                                                 float* __restrict__ out, int n) {
    int node = (blockIdx.x * 256 + threadIdx.x) >> 3;
    int lane = threadIdx.x & 7;
    if (node >= n) return;
    int s0 = offsets[node], s1 = offsets[node + 1];
    float edc = ed[node];

    float x0s = lexp(es[node] + edc);
    float sA = x0s, sB = 0.f, sC = 0.f, sD = 0.f;
    float aA[8], aB[8], aC[8], aD[8];
#pragma unroll
    for (int i = 0; i < 8; i++) { aA[i] = 0.f; aB[i] = 0.f; aC[i] = 0.f; aD[i] = 0.f; }
    fma8(aA, h2v[(size_t)node * 8 + lane], x0s);

    int k = s0;
    if (s1 - k >= 4) {
        int r0 = csr_src[k], r1 = csr_src[k + 1], r2 = csr_src[k + 2], r3 = csr_src[k + 3];
        float e0 = es[r0], e1 = es[r1], e2 = es[r2], e3 = es[r3];
        uint4 v0 = h2v[(size_t)r0 * 8 + lane];
        uint4 v1 = h2v[(size_t)r1 * 8 + lane];
        uint4 v2 = h2v[(size_t)r2 * 8 + lane];
        uint4 v3 = h2v[(size_t)r3 * 8 + lane];
        k += 4;
        while (s1 - k >= 4) {
            int q0 = csr_src[k], q1 = csr_src[k + 1], q2 = csr_src[k + 2], q3 = csr_src[k + 3];
            float f0 = es[q0], f1 = es[q1], f2 = es[q2], f3 = es[q3];
            uint4 u0 = h2v[(size_t)q0 * 8 + lane];
            uint4 u1 = h2v[(size_t)q1 * 8 + lane];
            uint4 u2 = h2v[(size_t)q2 * 8 + lane];
            uint4 u3 = h2v[(size_t)q3 * 8 + lane];
            k += 4;
            float x0 = lexp(e0 + edc), x1 = lexp(e1 + edc);
            float x2 = lexp(e2 + edc), x3 = lexp(e3 + edc);
            sA += x0; sB += x1; sC += x2; sD += x3;
            fma8(aA, v0, x0);
            fma8(aB, v1, x1);
            fma8(aC, v2, x2);
            fma8(aD, v3, x3);
            e0 = f0; e1 = f1; e2 = f2; e3 = f3;
            v0 = u0; v1 = u1; v2 = u2; v3 = u3;
        }
        float x0 = lexp(e0 + edc), x1 = lexp(e1 + edc);
        float x2 = lexp(e2 + edc), x3 = lexp(e3 + edc);
        sA += x0; sB += x1; sC += x2; sD += x3;
        fma8(aA, v0, x0);
        fma8(aB, v1, x1);
        fma8(aC, v2, x2);
        fma8(aD, v3, x3);
    }
    for (; k < s1; k++) {
        int r = csr_src[k];
        float xv = lexp(es[r] + edc);
        sA += xv;
        fma8(aA, h2v[(size_t)r * 8 + lane], xv);
    }
    float s = (sA + sB) + (sC + sD);
    float rcp = 1.0f / s;
    float4 b0 = ((const float4*)bgp)[lane * 2];
    float4 b1 = ((const float4*)bgp)[lane * 2 + 1];
    float o[8];
    o[0] = fmaxf(((aA[0] + aB[0]) + (aC[0] + aD[0])) * rcp + b0.x, 0.f);
    o[1] = fmaxf(((aA[1] + aB[1]) + (aC[1] + aD[1])) * rcp + b0.y, 0.f);
    o[2] = fmaxf(((aA[2] + aB[2]) + (aC[2] + aD[2])) * rcp + b0.z, 0.f);
    o[3] = fmaxf(((aA[3] + aB[3]) + (aC[3] + aD[3])) * rcp + b0.w, 0.f);
    o[4] = fmaxf(((aA[4] + aB[4]) + (aC[4] + aD[4])) * rcp + b1.x, 0.f);
    o[5] = fmaxf(((aA[5] + aB[5]) + (aC[5] + aD[5])) * rcp + b1.y, 0.f);
    o[6] = fmaxf(((aA[6] + aB[6]) + (aC[6] + aD[6])) * rcp + b1.z, 0.f);
    o[7] = fmaxf(((aA[7] + aB[7]) + (aC[7] + aD[7])) * rcp + b1.w, 0.f);

    float p0 = 0.f, p1 = 0.f;
#pragma unroll
    for (int m2 = 0; m2 < 4; m2++) {
        float4 w = ((const float4*)wfcp)[lane * 4 + m2];
        p0 += o[2 * m2] * w.x + o[2 * m2 + 1] * w.z;
        p1 += o[2 * m2] * w.y + o[2 * m2 + 1] * w.w;
    }
#pragma unroll
    for (int m = 4; m; m >>= 1) {
        p0 += __shfl_xor(p0, m, 8);
        p1 += __shfl_xor(p1, m, 8);
    }
    if (lane == 0) {
        out[(size_t)node * 2 + 0] = p0 + bfc[0];
        out[(size_t)node * 2 + 1] = p1 + bfc[1];
    }
}

extern "C" void kernel_launch(void* const* d_in, const int* in_sizes, int n_in,
                              void* d_out, int out_size, void* d_ws, size_t ws_size,
                              hipStream_t stream) {
    const float* x     = (const float*)d_in[0];
    const int*   ei    = (const int*)d_in[1];
    const float* W1    = (const float*)d_in[2];
    const float* b1    = (const float*)d_in[3];
    const float* Wg    = (const float*)d_in[4];
    const float* a_src = (const float*)d_in[5];
    const float* a_dst = (const float*)d_in[6];
    const float* bg    = (const float*)d_in[7];
    const float* Wfc   = (const float*)d_in[8];
    const float* bfc   = (const float*)d_in[9];
    float* out = (float*)d_out;

    const int N = in_sizes[0] / IN_DIM;
    const int E = in_sizes[1] / 2;
    const int* rowi = ei;
    const int* coli = ei + E;
    const int ncb = (N + 255) >> 8;            // coarse buckets of 256 nodes

    auto alignup = [](char* p) { return (char*)(((uintptr_t)p + 15) & ~(uintptr_t)15); };

    // workspace layout
    char* wsb = (char*)d_ws;
    int*   offsets = (int*)wsb;                         // N+8
    float* dinv    = (float*)(offsets + N + 8);         // N
    float* es      = dinv + N;                          // N
    float* ed      = es + N;                            // N
    float* h1s     = ed + N;                            // N (f32 row scales, 400 KB)
    int*   ghist   = (int*)(h1s + N);                   // NCB_MAX
    int*   cstart  = ghist + NCB_MAX;                   // NCB_MAX+2
    int*   gcursor = cstart + NCB_MAX + 2;              // NCB_MAX
    float* b1p     = (float*)(gcursor + NCB_MAX);       // 128
    float* bgp     = b1p + 128;                         // 64
    float2* wfcp   = (float2*)(bgp + 64);               // 64 float2
    uint4* wfrag   = (uint4*)alignup((char*)(wfcp + 64));   // 3072 uint4 (48 KB)
    uint4* wg2frag = wfrag + 3072;                      // 1024 uint4 (16 KB)
    int*   csr_src = (int*)(wg2frag + 1024);            // E
    unsigned* ebuf = (unsigned*)(csr_src + E);          // E (packed row<<8|local)
    unsigned char* h1p8 = (unsigned char*)alignup((char*)(ebuf + E)); // N*128 bytes (int8, perm)
    uint4* gb      = (uint4*)alignup((char*)(h1p8 + (size_t)N * 128)); // N*16 uint4
    unsigned* h2b  = (unsigned*)h1p8;  // alias: h1p8 dead after gcn_gather; h2b = N*32 words

    hipMemsetAsync(ghist, 0, NCB_MAX * 4, stream);

    const int nbE = (E + EPB - 1) / EPB;

    // 1) CSR build: coarse hist -> scan -> privatized scatter -> fused fine pass
    chist<<<nbE, 256, 0, stream>>>(coli, E, ghist, ncb);
    cscan<<<1, NCB_MAX, 0, stream>>>(ghist, cstart, gcursor, ncb, E);
    pass1_scatter<<<nbE, 256, 0, stream>>>(rowi, coli, E, gcursor, ebuf, ncb);
    pass2_all<<<ncb, 256, 0, stream>>>(ebuf, cstart, offsets, dinv, csr_src, N, E);

    // 2) weight prep (single dispatch)
    wprep_all<<<16, 256, 0, stream>>>(W1, b1, Wg, bg, Wfc, wfrag, b1p, wg2frag, bgp, wfcp);

    // 3) h1p8 = int8-row-quant((x @ W1) * dinv[row]) via LDS-free MFMA
    gemm1_mfma<<<(N + 63) / 64, 256, 0, stream>>>(x, wfrag, dinv, h1p8, h1s, N);

    // 4) GCN gather (int8 payload + L2-resident f32 row scales) -> bf16 g (perm layout)
    gcn_gather<<<(N + 15) / 16, 256, 0, stream>>>(offsets, csr_src, (const uint2*)h1p8,
                                                  h1s, dinv, b1p, gb, N);

    // 5) h2b = bf16(g @ Wg) via LDS-free MFMA, fused es/ed epilogue
    gemm2_mfma<<<(N + 63) / 64, 256, 0, stream>>>(gb, wg2frag, a_src, a_dst, h2b, es, ed, N);

    // 6) fused GAT: unnormalized-softmax gather + relu + final FC (bf16 h2 rows)
    gat_fused<<<(N + 31) / 32, 256, 0, stream>>>(offsets, csr_src, (const uint4*)h2b,
                                                 es, ed, bgp, wfcp, bfc, out, N);
}

// Round 8
// 321.256 us; speedup vs baseline: 1.2381x; 1.0096x over previous
//
#include <hip/hip_runtime.h>
#include <math.h>

#define NSL 0.2f   // leaky relu negative slope
#define IN_DIM 165
#define HID 128
#define OUT_H 64
#define NCB_MAX 512 // max coarse buckets (N <= 131072)
#define EPB 4096    // edges per pass1 block

typedef __attribute__((ext_vector_type(8))) short bf16x8;
typedef __attribute__((ext_vector_type(4))) float f32x4;

// ---------- bf16 pack (round-to-nearest-even) ----------
__device__ inline unsigned pack_bf16(float a, float b) {
    unsigned ua = __float_as_uint(a);
    ua += 0x7FFFu + ((ua >> 16) & 1u);
    unsigned ub = __float_as_uint(b);
    ub += 0x7FFFu + ((ub >> 16) & 1u);
    return (ua >> 16) | (ub & 0xFFFF0000u);
}

// column permutation of the packed layouts: stored bf16 index i -> original col.
__device__ __host__ inline int pcol(int i) {
    int j = i >> 1, odd = i & 1;
    return 32 * (j >> 4) + (j & 15) + 16 * odd;
}

// ---------- coarse histogram (LDS-privatized) ----------
__global__ __launch_bounds__(256) void chist(const int* __restrict__ coli, int E,
                                             int* __restrict__ ghist, int ncb) {
    __shared__ int h[NCB_MAX];
    for (int i = threadIdx.x; i < ncb; i += 256) h[i] = 0;
    __syncthreads();
    int e0 = blockIdx.x * EPB;
    int e1 = min(e0 + EPB, E);
    for (int e = e0 + threadIdx.x; e < e1; e += 256)
        atomicAdd(&h[coli[e] >> 8], 1);
    __syncthreads();
    for (int i = threadIdx.x; i < ncb; i += 256)
        if (h[i]) atomicAdd(&ghist[i], h[i]);
}

// ---------- 1-block scan of coarse histogram -> cstart, gcursor ----------
__global__ __launch_bounds__(NCB_MAX) void cscan(const int* __restrict__ ghist,
                                                 int* __restrict__ cstart,
                                                 int* __restrict__ gcursor,
                                                 int ncb, int E) {
    __shared__ int tmp[NCB_MAX];
    int tid = threadIdx.x;
    int v = (tid < ncb) ? ghist[tid] : 0;
    tmp[tid] = v;
    __syncthreads();
    for (int off = 1; off < NCB_MAX; off <<= 1) {
        int t = (tid >= off) ? tmp[tid - off] : 0;
        __syncthreads();
        tmp[tid] += t;
        __syncthreads();
    }
    if (tid < ncb) {
        int excl = tmp[tid] - v;
        cstart[tid] = excl;
        gcursor[tid] = excl;
    }
    if (tid == ncb - 1) cstart[ncb] = E;
}

// ---------- pass1: block-privatized scatter into coarse buckets ----------
// ebuf value = (row << 8) | (col & 255)   (requires N < 2^24)
__global__ __launch_bounds__(256) void pass1_scatter(const int* __restrict__ rowi,
                                                     const int* __restrict__ coli, int E,
                                                     int* __restrict__ gcursor,
                                                     unsigned* __restrict__ ebuf, int ncb) {
    __shared__ int hist[NCB_MAX];
    __shared__ int base[NCB_MAX];
    int e0 = blockIdx.x * EPB;
    int e1 = min(e0 + EPB, E);
    for (int i = threadIdx.x; i < ncb; i += 256) hist[i] = 0;
    __syncthreads();
    for (int e = e0 + threadIdx.x; e < e1; e += 256)
        atomicAdd(&hist[coli[e] >> 8], 1);
    __syncthreads();
    for (int i = threadIdx.x; i < ncb; i += 256) {
        int h = hist[i];
        base[i] = h ? atomicAdd(&gcursor[i], h) : 0;
        hist[i] = 0;
    }
    __syncthreads();
    for (int e = e0 + threadIdx.x; e < e1; e += 256) {
        int c = coli[e];
        int cb = c >> 8;
        int rank = atomicAdd(&hist[cb], 1);
        ebuf[base[cb] + rank] = ((unsigned)rowi[e] << 8) | (unsigned)(c & 255);
    }
}

// ---------- fused pass2: count -> local scan -> offsets/dinv -> rank+fill ----------
__global__ __launch_bounds__(256) void pass2_all(const unsigned* __restrict__ ebuf,
                                                 const int* __restrict__ cstart,
                                                 int* __restrict__ offsets,
                                                 float* __restrict__ dinv,
                                                 int* __restrict__ csr_src,
                                                 int n, int E) {
    __shared__ int cnt[256];
    __shared__ int scan[256];
    __shared__ int offs[256];
    const int tid = threadIdx.x;
    const int cb = blockIdx.x;
    cnt[tid] = 0;
    __syncthreads();
    int s = cstart[cb], e1 = cstart[cb + 1];
    for (int e = s + tid; e < e1; e += 256)
        atomicAdd(&cnt[ebuf[e] & 255u], 1);
    __syncthreads();
    int v = cnt[tid];
    scan[tid] = v;
    __syncthreads();
#pragma unroll
    for (int off = 1; off < 256; off <<= 1) {
        int t = (tid >= off) ? scan[tid - off] : 0;
        __syncthreads();
        scan[tid] += t;
        __syncthreads();
    }
    int off0 = s + scan[tid] - v;   // global exclusive offset for this node
    offs[tid] = off0;
    int node = (cb << 8) + tid;
    if (node < n) {
        offsets[node] = off0;
        dinv[node] = rsqrtf((float)v + 1.0f);   // +1 = self loop
    }
    if (cb == 0 && tid == 0) offsets[n] = E;
    cnt[tid] = 0;
    __syncthreads();
    for (int e = s + tid; e < e1; e += 256) {
        unsigned u = ebuf[e];
        int local = u & 255u;
        int rank = atomicAdd(&cnt[local], 1);
        csr_src[offs[local] + rank] = (int)(u >> 8);
    }
}

// ---------- weight prep (one dispatch): W1/Wg bf16 fragments + permuted b1/bg/Wfc ----------
__global__ __launch_bounds__(256) void wprep_all(const float* __restrict__ W1,
                                                 const float* __restrict__ b1,
                                                 const float* __restrict__ Wg,
                                                 const float* __restrict__ bg,
                                                 const float* __restrict__ Wfc,
                                                 uint4* __restrict__ wfrag,
                                                 float* __restrict__ b1p,
                                                 uint4* __restrict__ wg2frag,
                                                 float* __restrict__ bgp,
                                                 float2* __restrict__ wfcp) {
    int idx = blockIdx.x * 256 + threadIdx.x;
    if (idx < 3072) {
        int q = idx & 3, n = (idx >> 2) & 127, c = idx >> 9;
        int k0 = c * 32 + q * 8;
        float f[8];
#pragma unroll
        for (int j = 0; j < 8; j++) {
            int k = k0 + j;
            f[j] = (k < IN_DIM) ? W1[k * 128 + n] : 0.f;
        }
        uint4 u;
        u.x = pack_bf16(f[0], f[1]);
        u.y = pack_bf16(f[2], f[3]);
        u.z = pack_bf16(f[4], f[5]);
        u.w = pack_bf16(f[6], f[7]);
        wfrag[idx] = u;
    } else if (idx < 4096) {
        int i2 = idx - 3072;
        int q = i2 & 3, n = (i2 >> 2) & 63, c = i2 >> 8;
        float f[8];
#pragma unroll
        for (int j = 0; j < 8; j++) {
            int ks = c * 32 + q * 8 + j;
            f[j] = Wg[pcol(ks) * 64 + n];
        }
        uint4 u;
        u.x = pack_bf16(f[0], f[1]);
        u.y = pack_bf16(f[2], f[3]);
        u.z = pack_bf16(f[4], f[5]);
        u.w = pack_bf16(f[6], f[7]);
        wg2frag[i2] = u;
    }
    if (idx < 128) b1p[idx] = b1[pcol(idx)];
    if (idx < 64) {
        int o = pcol(idx);
        bgp[idx] = bg[o];
        wfcp[idx] = make_float2(Wfc[o * 2], Wfc[o * 2 + 1]);
    }
}

// ---------- GEMM1 via bf16 MFMA, LDS-free, x read directly (fused cvt) ----------
// Epilogue: int8 quantization, one f32 scale per row (h1s, L2-resident).
__global__ __launch_bounds__(256) void gemm1_mfma(const float* __restrict__ x,
                                                  const uint4* __restrict__ wfrag,
                                                  const float* __restrict__ dinv,
                                                  unsigned char* __restrict__ h1p8,
                                                  float* __restrict__ h1s, int M) {
    const int t = threadIdx.x;
    const int wave = t >> 6;
    const int lane = t & 63;
    const int l16 = lane & 15;
    const int quad = lane >> 4;
    const int rowbase = blockIdx.x * 64 + wave * 16;

    int arow = rowbase + l16;
    if (arow >= M) arow = M - 1;
    const float* xr = x + (size_t)arow * IN_DIM;

    f32x4 acc[8];
#pragma unroll
    for (int nt = 0; nt < 8; nt++) acc[nt] = (f32x4){0.f, 0.f, 0.f, 0.f};

#pragma unroll
    for (int c = 0; c < 6; c++) {
        int k0 = c * 32 + quad * 8;
        float f[8];
#pragma unroll
        for (int j = 0; j < 8; j++)
            f[j] = (k0 + j < IN_DIM) ? xr[k0 + j] : 0.f;
        uint4 au;
        au.x = pack_bf16(f[0], f[1]);
        au.y = pack_bf16(f[2], f[3]);
        au.z = pack_bf16(f[4], f[5]);
        au.w = pack_bf16(f[6], f[7]);
        bf16x8 a = __builtin_bit_cast(bf16x8, au);
#pragma unroll
        for (int nt = 0; nt < 8; nt++) {
            uint4 bu = wfrag[(size_t)((c * 128 + nt * 16 + l16) * 4 + quad)];
            bf16x8 b = __builtin_bit_cast(bf16x8, bu);
            acc[nt] = __builtin_amdgcn_mfma_f32_16x16x32_bf16(a, b, acc[nt], 0, 0, 0);
        }
    }

#pragma unroll
    for (int r = 0; r < 4; r++) {
        int row = rowbase + quad * 4 + r;
        if (row < M) {
            float s = dinv[row];
            float v[8];
#pragma unroll
            for (int nt = 0; nt < 8; nt++) v[nt] = acc[nt][r] * s;
            float gm = fabsf(v[0]);
#pragma unroll
            for (int nt = 1; nt < 8; nt++) gm = fmaxf(gm, fabsf(v[nt]));
            gm = fmaxf(gm, __shfl_xor(gm, 1, 16));
            gm = fmaxf(gm, __shfl_xor(gm, 2, 16));
            gm = fmaxf(gm, __shfl_xor(gm, 4, 16));
            gm = fmaxf(gm, __shfl_xor(gm, 8, 16));
            float inv = gm > 0.f ? 127.0f / gm : 0.f;
            unsigned short* hr = (unsigned short*)(h1p8 + (size_t)row * 128);
#pragma unroll
            for (int p = 0; p < 4; p++) {
                int q0 = (int)rintf(v[2 * p] * inv);
                int q1 = (int)rintf(v[2 * p + 1] * inv);
                hr[p * 16 + l16] = (unsigned short)((q0 & 0xff) | ((q1 & 0xff) << 8));
            }
            if (l16 == 0) h1s[row] = gm * (1.0f / 127.0f);
        }
    }
}

// 8 int8 -> f32, scaled accumulate (s = row scale)
__device__ inline void fma8i8(float* a, uint2 u, float s) {
    a[0] = fmaf((float)(char)(u.x), s, a[0]);
    a[1] = fmaf((float)(char)(u.x >> 8), s, a[1]);
    a[2] = fmaf((float)(char)(u.x >> 16), s, a[2]);
    a[3] = fmaf((float)(char)(u.x >> 24), s, a[3]);
    a[4] = fmaf((float)(char)(u.y), s, a[4]);
    a[5] = fmaf((float)(char)(u.y >> 8), s, a[5]);
    a[6] = fmaf((float)(char)(u.y >> 16), s, a[6]);
    a[7] = fmaf((float)(char)(u.y >> 24), s, a[7]);
}

// 4 bf16 -> f32, weighted accumulate
__device__ inline void fma4(float* a, uint2 u, float w) {
    a[0] = fmaf(__uint_as_float(u.x << 16), w, a[0]);
    a[1] = fmaf(__uint_as_float(u.x & 0xFFFF0000u), w, a[1]);
    a[2] = fmaf(__uint_as_float(u.y << 16), w, a[2]);
    a[3] = fmaf(__uint_as_float(u.y & 0xFFFF0000u), w, a[3]);
}

__device__ inline float lexp(float e) {
    e = e > 0.f ? e : NSL * e;
    return __expf(e);
}

// ---------- GCN gather: quarter-wave per dst node, int8+row-scale, deep pipeline ----------
// Double-buffered 8-wide batches: 16 row-fetches (2 KB/group) in flight.
// Tail (<8 edges) is one predicated 8-batch (all loads issued at once).
__global__ __launch_bounds__(256) void gcn_gather(const int* __restrict__ offsets,
                                                  const int* __restrict__ csr_src,
                                                  const uint2* __restrict__ h1v8,
                                                  const float* __restrict__ h1s,
                                                  const float* __restrict__ dinv,
                                                  const float* __restrict__ b1p,
                                                  uint4* __restrict__ gb, int n) {
    int node = (blockIdx.x * 256 + threadIdx.x) >> 4;
    int lane = threadIdx.x & 15;
    if (node >= n) return;
    int s0 = offsets[node], s1 = offsets[node + 1];

    float a0[8], a1[8], a2[8], a3[8];
#pragma unroll
    for (int i = 0; i < 8; i++) { a0[i] = 0.f; a1[i] = 0.f; a2[i] = 0.f; a3[i] = 0.f; }
    fma8i8(a0, h1v8[(size_t)node * 16 + lane], h1s[node]);   // self loop

    int k = s0;
    if (s1 - k >= 8) {
        uint2 vA[8];
        float wA[8];
        {
            int r[8];
#pragma unroll
            for (int j = 0; j < 8; j++) r[j] = csr_src[k + j];
#pragma unroll
            for (int j = 0; j < 8; j++) vA[j] = h1v8[(size_t)r[j] * 16 + lane];
#pragma unroll
            for (int j = 0; j < 8; j++) wA[j] = h1s[r[j]];
        }
        k += 8;
        while (s1 - k >= 8) {
            uint2 vB[8];
            float wB[8];
            {
                int r[8];
#pragma unroll
                for (int j = 0; j < 8; j++) r[j] = csr_src[k + j];
#pragma unroll
                for (int j = 0; j < 8; j++) vB[j] = h1v8[(size_t)r[j] * 16 + lane];
#pragma unroll
                for (int j = 0; j < 8; j++) wB[j] = h1s[r[j]];
            }
            k += 8;
            fma8i8(a0, vA[0], wA[0]);
            fma8i8(a1, vA[1], wA[1]);
            fma8i8(a2, vA[2], wA[2]);
            fma8i8(a3, vA[3], wA[3]);
            fma8i8(a0, vA[4], wA[4]);
            fma8i8(a1, vA[5], wA[5]);
            fma8i8(a2, vA[6], wA[6]);
            fma8i8(a3, vA[7], wA[7]);
#pragma unroll
            for (int j = 0; j < 8; j++) { vA[j] = vB[j]; wA[j] = wB[j]; }
        }
        fma8i8(a0, vA[0], wA[0]);
        fma8i8(a1, vA[1], wA[1]);
        fma8i8(a2, vA[2], wA[2]);
        fma8i8(a3, vA[3], wA[3]);
        fma8i8(a0, vA[4], wA[4]);
        fma8i8(a1, vA[5], wA[5]);
        fma8i8(a2, vA[6], wA[6]);
        fma8i8(a3, vA[7], wA[7]);
    }
    int m = s1 - k;
    if (m > 0) {
        int r[8];
#pragma unroll
        for (int j = 0; j < 8; j++) r[j] = csr_src[j < m ? k + j : k];
        uint2 v[8];
#pragma unroll
        for (int j = 0; j < 8; j++) v[j] = h1v8[(size_t)r[j] * 16 + lane];
        float w[8];
#pragma unroll
        for (int j = 0; j < 8; j++) w[j] = (j < m) ? h1s[r[j]] : 0.f;
        fma8i8(a0, v[0], w[0]);
        fma8i8(a1, v[1], w[1]);
        fma8i8(a2, v[2], w[2]);
        fma8i8(a3, v[3], w[3]);
        fma8i8(a0, v[4], w[4]);
        fma8i8(a1, v[5], w[5]);
        fma8i8(a2, v[6], w[6]);
        fma8i8(a3, v[7], w[7]);
    }

    float dc = dinv[node];
    float4 bb0 = ((const float4*)b1p)[lane * 2];
    float4 bb1 = ((const float4*)b1p)[lane * 2 + 1];
    float o[8];
    o[0] = fmaxf(((a0[0] + a1[0]) + (a2[0] + a3[0])) * dc + bb0.x, 0.f);
    o[1] = fmaxf(((a0[1] + a1[1]) + (a2[1] + a3[1])) * dc + bb0.y, 0.f);
    o[2] = fmaxf(((a0[2] + a1[2]) + (a2[2] + a3[2])) * dc + bb0.z, 0.f);
    o[3] = fmaxf(((a0[3] + a1[3]) + (a2[3] + a3[3])) * dc + bb0.w, 0.f);
    o[4] = fmaxf(((a0[4] + a1[4]) + (a2[4] + a3[4])) * dc + bb1.x, 0.f);
    o[5] = fmaxf(((a0[5] + a1[5]) + (a2[5] + a3[5])) * dc + bb1.y, 0.f);
    o[6] = fmaxf(((a0[6] + a1[6]) + (a2[6] + a3[6])) * dc + bb1.z, 0.f);
    o[7] = fmaxf(((a0[7] + a1[7]) + (a2[7] + a3[7])) * dc + bb1.w, 0.f);
    uint4 pk;
    pk.x = pack_bf16(o[0], o[1]);
    pk.y = pack_bf16(o[2], o[3]);
    pk.z = pack_bf16(o[4], o[5]);
    pk.w = pack_bf16(o[6], o[7]);
    gb[(size_t)node * 16 + lane] = pk;
}

// ---------- GEMM2 via bf16 MFMA, LDS-free; fused es/ed; bf16 h2 out ----------
__global__ __launch_bounds__(256) void gemm2_mfma(const uint4* __restrict__ gb4,
                                                  const uint4* __restrict__ wg2frag,
                                                  const float* __restrict__ a_src,
                                                  const float* __restrict__ a_dst,
                                                  unsigned* __restrict__ h2b,
                                                  float* __restrict__ es,
                                                  float* __restrict__ ed, int M) {
    const int t = threadIdx.x;
    const int wave = t >> 6;
    const int lane = t & 63;
    const int l16 = lane & 15;
    const int quad = lane >> 4;
    const int rowbase = blockIdx.x * 64 + wave * 16;

    int arow = rowbase + l16;
    if (arow >= M) arow = M - 1;

    f32x4 acc[4];
#pragma unroll
    for (int nt = 0; nt < 4; nt++) acc[nt] = (f32x4){0.f, 0.f, 0.f, 0.f};

#pragma unroll
    for (int c = 0; c < 4; c++) {
        uint4 au = gb4[(size_t)arow * 16 + c * 4 + quad];
        bf16x8 a = __builtin_bit_cast(bf16x8, au);
#pragma unroll
        for (int nt = 0; nt < 4; nt++) {
            uint4 bu = wg2frag[(size_t)((c * 64 + nt * 16 + l16) * 4 + quad)];
            bf16x8 b = __builtin_bit_cast(bf16x8, bu);
            acc[nt] = __builtin_amdgcn_mfma_f32_16x16x32_bf16(a, b, acc[nt], 0, 0, 0);
        }
    }

    float as0 = a_src[l16], as1 = a_src[16 + l16], as2 = a_src[32 + l16], as3 = a_src[48 + l16];
    float ad0 = a_dst[l16], ad1 = a_dst[16 + l16], ad2 = a_dst[32 + l16], ad3 = a_dst[48 + l16];

#pragma unroll
    for (int r = 0; r < 4; r++) {
        int row = rowbase + quad * 4 + r;
        float ps = acc[0][r] * as0 + acc[1][r] * as1 + acc[2][r] * as2 + acc[3][r] * as3;
        float pd = acc[0][r] * ad0 + acc[1][r] * ad1 + acc[2][r] * ad2 + acc[3][r] * ad3;
#pragma unroll
        for (int m = 8; m; m >>= 1) {
            ps += __shfl_xor(ps, m, 16);
            pd += __shfl_xor(pd, m, 16);
        }
        if (row < M) {
            h2b[(size_t)row * 32 + l16]      = pack_bf16(acc[0][r], acc[1][r]);
            h2b[(size_t)row * 32 + 16 + l16] = pack_bf16(acc[2][r], acc[3][r]);
            if (l16 == 0) { es[row] = ps; ed[row] = pd; }
        }
    }
}

// ---------- fused GAT: 16 lanes/node, deep pipeline (gcn_gather structure) ----------
// Per-lane payload is uint2 (4 bf16) so the 8-wide double-buffered batch fits
// the register budget: 16 rows (2 KB/group) in flight. es is row-broadcast so
// ssum stays lane-replicated (no reduction). FC reduces over 16 lanes.
__global__ __launch_bounds__(256) void gat_fused(const int* __restrict__ offsets,
                                                 const int* __restrict__ csr_src,
                                                 const uint2* __restrict__ h2v,  // row = 16 uint2
                                                 const float* __restrict__ es,
                                                 const float* __restrict__ ed,
                                                 const float* __restrict__ bgp,
                                                 const float2* __restrict__ wfcp,
                                                 const float* __restrict__ bfc,
                                                 float* __restrict__ out, int n) {
    int node = (blockIdx.x * 256 + threadIdx.x) >> 4;
    int lane = threadIdx.x & 15;
    if (node >= n) return;
    int s0 = offsets[node], s1 = offsets[node + 1];
    float edc = ed[node];

    float x0s = lexp(es[node] + edc);
    float sA = x0s, sB = 0.f, sC = 0.f, sD = 0.f;
    float aA[4], aB[4], aC[4], aD[4];
#pragma unroll
    for (int i = 0; i < 4; i++) { aA[i] = 0.f; aB[i] = 0.f; aC[i] = 0.f; aD[i] = 0.f; }
    fma4(aA, h2v[(size_t)node * 16 + lane], x0s);   // self loop

    int k = s0;
    if (s1 - k >= 8) {
        uint2 vA[8];
        float eA[8];
        {
            int r[8];
#pragma unroll
            for (int j = 0; j < 8; j++) r[j] = csr_src[k + j];
#pragma unroll
            for (int j = 0; j < 8; j++) vA[j] = h2v[(size_t)r[j] * 16 + lane];
#pragma unroll
            for (int j = 0; j < 8; j++) eA[j] = es[r[j]];
        }
        k += 8;
        while (s1 - k >= 8) {
            uint2 vB[8];
            float eB[8];
            {
                int r[8];
#pragma unroll
                for (int j = 0; j < 8; j++) r[j] = csr_src[k + j];
#pragma unroll
                for (int j = 0; j < 8; j++) vB[j] = h2v[(size_t)r[j] * 16 + lane];
#pragma unroll
                for (int j = 0; j < 8; j++) eB[j] = es[r[j]];
            }
            k += 8;
            float x0 = lexp(eA[0] + edc), x1 = lexp(eA[1] + edc);
            float x2 = lexp(eA[2] + edc), x3 = lexp(eA[3] + edc);
            float x4 = lexp(eA[4] + edc), x5 = lexp(eA[5] + edc);
            float x6 = lexp(eA[6] + edc), x7 = lexp(eA[7] + edc);
            sA += x0; sB += x1; sC += x2; sD += x3;
            sA += x4; sB += x5; sC += x6; sD += x7;
            fma4(aA, vA[0], x0);
            fma4(aB, vA[1], x1);
            fma4(aC, vA[2], x2);
            fma4(aD, vA[3], x3);
            fma4(aA, vA[4], x4);
            fma4(aB, vA[5], x5);
            fma4(aC, vA[6], x6);
            fma4(aD, vA[7], x7);
#pragma unroll
            for (int j = 0; j < 8; j++) { vA[j] = vB[j]; eA[j] = eB[j]; }
        }
        float x0 = lexp(eA[0] + edc), x1 = lexp(eA[1] + edc);
        float x2 = lexp(eA[2] + edc), x3 = lexp(eA[3] + edc);
        float x4 = lexp(eA[4] + edc), x5 = lexp(eA[5] + edc);
        float x6 = lexp(eA[6] + edc), x7 = lexp(eA[7] + edc);
        sA += x0; sB += x1; sC += x2; sD += x3;
        sA += x4; sB += x5; sC += x6; sD += x7;
        fma4(aA, vA[0], x0);
        fma4(aB, vA[1], x1);
        fma4(aC, vA[2], x2);
        fma4(aD, vA[3], x3);
        fma4(aA, vA[4], x4);
        fma4(aB, vA[5], x5);
        fma4(aC, vA[6], x6);
        fma4(aD, vA[7], x7);
    }
    int m = s1 - k;
    if (m > 0) {
        // predicated tail batch: all loads issued back-to-back, weight 0 for pads
        int r[8];
#pragma unroll
        for (int j = 0; j < 8; j++) r[j] = csr_src[j < m ? k + j : k];
        uint2 v[8];
#pragma unroll
        for (int j = 0; j < 8; j++) v[j] = h2v[(size_t)r[j] * 16 + lane];
        float ev[8];
#pragma unroll
        for (int j = 0; j < 8; j++) ev[j] = es[r[j]];
        float x0 = (0 < m) ? lexp(ev[0] + edc) : 0.f;
        float x1 = (1 < m) ? lexp(ev[1] + edc) : 0.f;
        float x2 = (2 < m) ? lexp(ev[2] + edc) : 0.f;
        float x3 = (3 < m) ? lexp(ev[3] + edc) : 0.f;
        float x4 = (4 < m) ? lexp(ev[4] + edc) : 0.f;
        float x5 = (5 < m) ? lexp(ev[5] + edc) : 0.f;
        float x6 = (6 < m) ? lexp(ev[6] + edc) : 0.f;
        float x7 = (7 < m) ? lexp(ev[7] + edc) : 0.f;
        sA += x0; sB += x1; sC += x2; sD += x3;
        sA += x4; sB += x5; sC += x6; sD += x7;
        fma4(aA, v[0], x0);
        fma4(aB, v[1], x1);
        fma4(aC, v[2], x2);
        fma4(aD, v[3], x3);
        fma4(aA, v[4], x4);
        fma4(aB, v[5], x5);
        fma4(aC, v[6], x6);
        fma4(aD, v[7], x7);
    }

    float s = (sA + sB) + (sC + sD);
    float rcp = 1.0f / s;
    float4 bb = ((const float4*)bgp)[lane];       // bgp[4*lane .. 4*lane+3]
    float o[4];
    o[0] = fmaxf(((aA[0] + aB[0]) + (aC[0] + aD[0])) * rcp + bb.x, 0.f);
    o[1] = fmaxf(((aA[1] + aB[1]) + (aC[1] + aD[1])) * rcp + bb.y, 0.f);
    o[2] = fmaxf(((aA[2] + aB[2]) + (aC[2] + aD[2])) * rcp + bb.z, 0.f);
    o[3] = fmaxf(((aA[3] + aB[3]) + (aC[3] + aD[3])) * rcp + bb.w, 0.f);

    // FC: lane owns stored cols 4*lane..4*lane+3; wfcp[i] = (Wfc[pcol(i)][0], [1])
    float4 w01 = ((const float4*)wfcp)[lane * 2];      // wfcp[4l], wfcp[4l+1]
    float4 w23 = ((const float4*)wfcp)[lane * 2 + 1];  // wfcp[4l+2], wfcp[4l+3]
    float p0 = o[0] * w01.x + o[1] * w01.z + o[2] * w23.x + o[3] * w23.z;
    float p1 = o[0] * w01.y + o[1] * w01.w + o[2] * w23.y + o[3] * w23.w;
#pragma unroll
    for (int mm = 8; mm; mm >>= 1) {
        p0 += __shfl_xor(p0, mm, 16);
        p1 += __shfl_xor(p1, mm, 16);
    }
    if (lane == 0) {
        out[(size_t)node * 2 + 0] = p0 + bfc[0];
        out[(size_t)node * 2 + 1] = p1 + bfc[1];
    }
}

extern "C" void kernel_launch(void* const* d_in, const int* in_sizes, int n_in,
                              void* d_out, int out_size, void* d_ws, size_t ws_size,
                              hipStream_t stream) {
    const float* x     = (const float*)d_in[0];
    const int*   ei    = (const int*)d_in[1];
    const float* W1    = (const float*)d_in[2];
    const float* b1    = (const float*)d_in[3];
    const float* Wg    = (const float*)d_in[4];
    const float* a_src = (const float*)d_in[5];
    const float* a_dst = (const float*)d_in[6];
    const float* bg    = (const float*)d_in[7];
    const float* Wfc   = (const float*)d_in[8];
    const float* bfc   = (const float*)d_in[9];
    float* out = (float*)d_out;

    const int N = in_sizes[0] / IN_DIM;
    const int E = in_sizes[1] / 2;
    const int* rowi = ei;
    const int* coli = ei + E;
    const int ncb = (N + 255) >> 8;            // coarse buckets of 256 nodes

    auto alignup = [](char* p) { return (char*)(((uintptr_t)p + 15) & ~(uintptr_t)15); };

    // workspace layout
    char* wsb = (char*)d_ws;
    int*   offsets = (int*)wsb;                         // N+8
    float* dinv    = (float*)(offsets + N + 8);         // N
    float* es      = dinv + N;                          // N
    float* ed      = es + N;                            // N
    float* h1s     = ed + N;                            // N (f32 row scales, 400 KB)
    int*   ghist   = (int*)(h1s + N);                   // NCB_MAX
    int*   cstart  = ghist + NCB_MAX;                   // NCB_MAX+2
    int*   gcursor = cstart + NCB_MAX + 2;              // NCB_MAX
    float* b1p     = (float*)(gcursor + NCB_MAX);       // 128
    float* bgp     = b1p + 128;                         // 64
    float2* wfcp   = (float2*)(bgp + 64);               // 64 float2
    uint4* wfrag   = (uint4*)alignup((char*)(wfcp + 64));   // 3072 uint4 (48 KB)
    uint4* wg2frag = wfrag + 3072;                      // 1024 uint4 (16 KB)
    int*   csr_src = (int*)(wg2frag + 1024);            // E
    unsigned* ebuf = (unsigned*)(csr_src + E);          // E (packed row<<8|local)
    unsigned char* h1p8 = (unsigned char*)alignup((char*)(ebuf + E)); // N*128 bytes (int8, perm)
    uint4* gb      = (uint4*)alignup((char*)(h1p8 + (size_t)N * 128)); // N*16 uint4
    unsigned* h2b  = (unsigned*)h1p8;  // alias: h1p8 dead after gcn_gather; h2b = N*32 words

    hipMemsetAsync(ghist, 0, NCB_MAX * 4, stream);

    const int nbE = (E + EPB - 1) / EPB;

    // 1) CSR build: coarse hist -> scan -> privatized scatter -> fused fine pass
    chist<<<nbE, 256, 0, stream>>>(coli, E, ghist, ncb);
    cscan<<<1, NCB_MAX, 0, stream>>>(ghist, cstart, gcursor, ncb, E);
    pass1_scatter<<<nbE, 256, 0, stream>>>(rowi, coli, E, gcursor, ebuf, ncb);
    pass2_all<<<ncb, 256, 0, stream>>>(ebuf, cstart, offsets, dinv, csr_src, N, E);

    // 2) weight prep (single dispatch)
    wprep_all<<<16, 256, 0, stream>>>(W1, b1, Wg, bg, Wfc, wfrag, b1p, wg2frag, bgp, wfcp);

    // 3) h1p8 = int8-row-quant((x @ W1) * dinv[row]) via LDS-free MFMA
    gemm1_mfma<<<(N + 63) / 64, 256, 0, stream>>>(x, wfrag, dinv, h1p8, h1s, N);

    // 4) GCN gather (int8 payload + L2-resident f32 row scales) -> bf16 g (perm layout)
    gcn_gather<<<(N + 15) / 16, 256, 0, stream>>>(offsets, csr_src, (const uint2*)h1p8,
                                                  h1s, dinv, b1p, gb, N);

    // 5) h2b = bf16(g @ Wg) via LDS-free MFMA, fused es/ed epilogue
    gemm2_mfma<<<(N + 63) / 64, 256, 0, stream>>>(gb, wg2frag, a_src, a_dst, h2b, es, ed, N);

    // 6) fused GAT: 16 lanes/node, deep-pipelined gather + relu + final FC
    gat_fused<<<(N + 15) / 16, 256, 0, stream>>>(offsets, csr_src, (const uint2*)h2b,
                                                 es, ed, bgp, wfcp, bfc, out, N);
}

// Round 9
// 311.963 us; speedup vs baseline: 1.2750x; 1.0298x over previous
//
#include <hip/hip_runtime.h>
#include <math.h>

#define NSL 0.2f   // leaky relu negative slope
#define IN_DIM 165
#define HID 128
#define OUT_H 64
#define NCB_MAX 512 // max coarse buckets (N <= 131072)
#define EPB 4096    // edges per pass1 block

typedef __attribute__((ext_vector_type(8))) short bf16x8;
typedef __attribute__((ext_vector_type(4))) float f32x4;

// ---------- bf16 pack (round-to-nearest-even) ----------
__device__ inline unsigned pack_bf16(float a, float b) {
    unsigned ua = __float_as_uint(a);
    ua += 0x7FFFu + ((ua >> 16) & 1u);
    unsigned ub = __float_as_uint(b);
    ub += 0x7FFFu + ((ub >> 16) & 1u);
    return (ua >> 16) | (ub & 0xFFFF0000u);
}

// column permutation of the packed layouts: stored bf16 index i -> original col.
__device__ __host__ inline int pcol(int i) {
    int j = i >> 1, odd = i & 1;
    return 32 * (j >> 4) + (j & 15) + 16 * odd;
}

// ---------- coarse histogram (LDS-privatized) ----------
__global__ __launch_bounds__(256) void chist(const int* __restrict__ coli, int E,
                                             int* __restrict__ ghist, int ncb) {
    __shared__ int h[NCB_MAX];
    for (int i = threadIdx.x; i < ncb; i += 256) h[i] = 0;
    __syncthreads();
    int e0 = blockIdx.x * EPB;
    int e1 = min(e0 + EPB, E);
    for (int e = e0 + threadIdx.x; e < e1; e += 256)
        atomicAdd(&h[coli[e] >> 8], 1);
    __syncthreads();
    for (int i = threadIdx.x; i < ncb; i += 256)
        if (h[i]) atomicAdd(&ghist[i], h[i]);
}

// ---------- 1-block scan of coarse histogram -> cstart, gcursor ----------
__global__ __launch_bounds__(NCB_MAX) void cscan(const int* __restrict__ ghist,
                                                 int* __restrict__ cstart,
                                                 int* __restrict__ gcursor,
                                                 int ncb, int E) {
    __shared__ int tmp[NCB_MAX];
    int tid = threadIdx.x;
    int v = (tid < ncb) ? ghist[tid] : 0;
    tmp[tid] = v;
    __syncthreads();
    for (int off = 1; off < NCB_MAX; off <<= 1) {
        int t = (tid >= off) ? tmp[tid - off] : 0;
        __syncthreads();
        tmp[tid] += t;
        __syncthreads();
    }
    if (tid < ncb) {
        int excl = tmp[tid] - v;
        cstart[tid] = excl;
        gcursor[tid] = excl;
    }
    if (tid == ncb - 1) cstart[ncb] = E;
}

// ---------- pass1: block-privatized scatter into coarse buckets ----------
// ebuf value = (row << 8) | (col & 255)   (requires N < 2^24)
__global__ __launch_bounds__(256) void pass1_scatter(const int* __restrict__ rowi,
                                                     const int* __restrict__ coli, int E,
                                                     int* __restrict__ gcursor,
                                                     unsigned* __restrict__ ebuf, int ncb) {
    __shared__ int hist[NCB_MAX];
    __shared__ int base[NCB_MAX];
    int e0 = blockIdx.x * EPB;
    int e1 = min(e0 + EPB, E);
    for (int i = threadIdx.x; i < ncb; i += 256) hist[i] = 0;
    __syncthreads();
    for (int e = e0 + threadIdx.x; e < e1; e += 256)
        atomicAdd(&hist[coli[e] >> 8], 1);
    __syncthreads();
    for (int i = threadIdx.x; i < ncb; i += 256) {
        int h = hist[i];
        base[i] = h ? atomicAdd(&gcursor[i], h) : 0;
        hist[i] = 0;
    }
    __syncthreads();
    for (int e = e0 + threadIdx.x; e < e1; e += 256) {
        int c = coli[e];
        int cb = c >> 8;
        int rank = atomicAdd(&hist[cb], 1);
        ebuf[base[cb] + rank] = ((unsigned)rowi[e] << 8) | (unsigned)(c & 255);
    }
}

// ---------- fused pass2: count -> local scan -> offsets/dinv -> rank+fill ----------
__global__ __launch_bounds__(256) void pass2_all(const unsigned* __restrict__ ebuf,
                                                 const int* __restrict__ cstart,
                                                 int* __restrict__ offsets,
                                                 float* __restrict__ dinv,
                                                 int* __restrict__ csr_src,
                                                 int n, int E) {
    __shared__ int cnt[256];
    __shared__ int scan[256];
    __shared__ int offs[256];
    const int tid = threadIdx.x;
    const int cb = blockIdx.x;
    cnt[tid] = 0;
    __syncthreads();
    int s = cstart[cb], e1 = cstart[cb + 1];
    for (int e = s + tid; e < e1; e += 256)
        atomicAdd(&cnt[ebuf[e] & 255u], 1);
    __syncthreads();
    int v = cnt[tid];
    scan[tid] = v;
    __syncthreads();
#pragma unroll
    for (int off = 1; off < 256; off <<= 1) {
        int t = (tid >= off) ? scan[tid - off] : 0;
        __syncthreads();
        scan[tid] += t;
        __syncthreads();
    }
    int off0 = s + scan[tid] - v;   // global exclusive offset for this node
    offs[tid] = off0;
    int node = (cb << 8) + tid;
    if (node < n) {
        offsets[node] = off0;
        dinv[node] = rsqrtf((float)v + 1.0f);   // +1 = self loop
    }
    if (cb == 0 && tid == 0) offsets[n] = E;
    cnt[tid] = 0;
    __syncthreads();
    for (int e = s + tid; e < e1; e += 256) {
        unsigned u = ebuf[e];
        int local = u & 255u;
        int rank = atomicAdd(&cnt[local], 1);
        csr_src[offs[local] + rank] = (int)(u >> 8);
    }
}

// ---------- weight prep (one dispatch): W1/Wg bf16 fragments + permuted b1/bg/Wfc ----------
__global__ __launch_bounds__(256) void wprep_all(const float* __restrict__ W1,
                                                 const float* __restrict__ b1,
                                                 const float* __restrict__ Wg,
                                                 const float* __restrict__ bg,
                                                 const float* __restrict__ Wfc,
                                                 uint4* __restrict__ wfrag,
                                                 float* __restrict__ b1p,
                                                 uint4* __restrict__ wg2frag,
                                                 float* __restrict__ bgp,
                                                 float2* __restrict__ wfcp) {
    int idx = blockIdx.x * 256 + threadIdx.x;
    if (idx < 3072) {
        int q = idx & 3, n = (idx >> 2) & 127, c = idx >> 9;
        int k0 = c * 32 + q * 8;
        float f[8];
#pragma unroll
        for (int j = 0; j < 8; j++) {
            int k = k0 + j;
            f[j] = (k < IN_DIM) ? W1[k * 128 + n] : 0.f;
        }
        uint4 u;
        u.x = pack_bf16(f[0], f[1]);
        u.y = pack_bf16(f[2], f[3]);
        u.z = pack_bf16(f[4], f[5]);
        u.w = pack_bf16(f[6], f[7]);
        wfrag[idx] = u;
    } else if (idx < 4096) {
        int i2 = idx - 3072;
        int q = i2 & 3, n = (i2 >> 2) & 63, c = i2 >> 8;
        float f[8];
#pragma unroll
        for (int j = 0; j < 8; j++) {
            int ks = c * 32 + q * 8 + j;
            f[j] = Wg[pcol(ks) * 64 + n];
        }
        uint4 u;
        u.x = pack_bf16(f[0], f[1]);
        u.y = pack_bf16(f[2], f[3]);
        u.z = pack_bf16(f[4], f[5]);
        u.w = pack_bf16(f[6], f[7]);
        wg2frag[i2] = u;
    }
    if (idx < 128) b1p[idx] = b1[pcol(idx)];
    if (idx < 64) {
        int o = pcol(idx);
        bgp[idx] = bg[o];
        wfcp[idx] = make_float2(Wfc[o * 2], Wfc[o * 2 + 1]);
    }
}

// ---------- GEMM1 via bf16 MFMA, LDS-free, x read directly (fused cvt) ----------
// Epilogue: int8 quantization, one f32 scale per row (h1s, L2-resident).
__global__ __launch_bounds__(256) void gemm1_mfma(const float* __restrict__ x,
                                                  const uint4* __restrict__ wfrag,
                                                  const float* __restrict__ dinv,
                                                  unsigned char* __restrict__ h1p8,
                                                  float* __restrict__ h1s, int M) {
    const int t = threadIdx.x;
    const int wave = t >> 6;
    const int lane = t & 63;
    const int l16 = lane & 15;
    const int quad = lane >> 4;
    const int rowbase = blockIdx.x * 64 + wave * 16;

    int arow = rowbase + l16;
    if (arow >= M) arow = M - 1;
    const float* xr = x + (size_t)arow * IN_DIM;

    f32x4 acc[8];
#pragma unroll
    for (int nt = 0; nt < 8; nt++) acc[nt] = (f32x4){0.f, 0.f, 0.f, 0.f};

#pragma unroll
    for (int c = 0; c < 6; c++) {
        int k0 = c * 32 + quad * 8;
        float f[8];
#pragma unroll
        for (int j = 0; j < 8; j++)
            f[j] = (k0 + j < IN_DIM) ? xr[k0 + j] : 0.f;
        uint4 au;
        au.x = pack_bf16(f[0], f[1]);
        au.y = pack_bf16(f[2], f[3]);
        au.z = pack_bf16(f[4], f[5]);
        au.w = pack_bf16(f[6], f[7]);
        bf16x8 a = __builtin_bit_cast(bf16x8, au);
#pragma unroll
        for (int nt = 0; nt < 8; nt++) {
            uint4 bu = wfrag[(size_t)((c * 128 + nt * 16 + l16) * 4 + quad)];
            bf16x8 b = __builtin_bit_cast(bf16x8, bu);
            acc[nt] = __builtin_amdgcn_mfma_f32_16x16x32_bf16(a, b, acc[nt], 0, 0, 0);
        }
    }

#pragma unroll
    for (int r = 0; r < 4; r++) {
        int row = rowbase + quad * 4 + r;
        if (row < M) {
            float s = dinv[row];
            float v[8];
#pragma unroll
            for (int nt = 0; nt < 8; nt++) v[nt] = acc[nt][r] * s;
            float gm = fabsf(v[0]);
#pragma unroll
            for (int nt = 1; nt < 8; nt++) gm = fmaxf(gm, fabsf(v[nt]));
            gm = fmaxf(gm, __shfl_xor(gm, 1, 16));
            gm = fmaxf(gm, __shfl_xor(gm, 2, 16));
            gm = fmaxf(gm, __shfl_xor(gm, 4, 16));
            gm = fmaxf(gm, __shfl_xor(gm, 8, 16));
            float inv = gm > 0.f ? 127.0f / gm : 0.f;
            unsigned short* hr = (unsigned short*)(h1p8 + (size_t)row * 128);
#pragma unroll
            for (int p = 0; p < 4; p++) {
                int q0 = (int)rintf(v[2 * p] * inv);
                int q1 = (int)rintf(v[2 * p + 1] * inv);
                hr[p * 16 + l16] = (unsigned short)((q0 & 0xff) | ((q1 & 0xff) << 8));
            }
            if (l16 == 0) h1s[row] = gm * (1.0f / 127.0f);
        }
    }
}

// 8 int8 -> f32, scaled accumulate (s = row scale)
__device__ inline void fma8i8(float* a, uint2 u, float s) {
    a[0] = fmaf((float)(char)(u.x), s, a[0]);
    a[1] = fmaf((float)(char)(u.x >> 8), s, a[1]);
    a[2] = fmaf((float)(char)(u.x >> 16), s, a[2]);
    a[3] = fmaf((float)(char)(u.x >> 24), s, a[3]);
    a[4] = fmaf((float)(char)(u.y), s, a[4]);
    a[5] = fmaf((float)(char)(u.y >> 8), s, a[5]);
    a[6] = fmaf((float)(char)(u.y >> 16), s, a[6]);
    a[7] = fmaf((float)(char)(u.y >> 24), s, a[7]);
}

// 4 int8 -> f32, scaled accumulate
__device__ inline void fma4i8(float* a, unsigned u, float s) {
    a[0] = fmaf((float)(char)(u), s, a[0]);
    a[1] = fmaf((float)(char)(u >> 8), s, a[1]);
    a[2] = fmaf((float)(char)(u >> 16), s, a[2]);
    a[3] = fmaf((float)(char)(u >> 24), s, a[3]);
}

__device__ inline float lexp(float e) {
    e = e > 0.f ? e : NSL * e;
    return __expf(e);
}

// ---------- GCN gather: quarter-wave per dst node, int8+row-scale, deep pipeline ----------
// Double-buffered 8-wide batches: 16 row-fetches (2 KB/group) in flight.
// Tail (<8 edges) is one predicated 8-batch (all loads issued at once).
__global__ __launch_bounds__(256) void gcn_gather(const int* __restrict__ offsets,
                                                  const int* __restrict__ csr_src,
                                                  const uint2* __restrict__ h1v8,
                                                  const float* __restrict__ h1s,
                                                  const float* __restrict__ dinv,
                                                  const float* __restrict__ b1p,
                                                  uint4* __restrict__ gb, int n) {
    int node = (blockIdx.x * 256 + threadIdx.x) >> 4;
    int lane = threadIdx.x & 15;
    if (node >= n) return;
    int s0 = offsets[node], s1 = offsets[node + 1];

    float a0[8], a1[8], a2[8], a3[8];
#pragma unroll
    for (int i = 0; i < 8; i++) { a0[i] = 0.f; a1[i] = 0.f; a2[i] = 0.f; a3[i] = 0.f; }
    fma8i8(a0, h1v8[(size_t)node * 16 + lane], h1s[node]);   // self loop

    int k = s0;
    if (s1 - k >= 8) {
        uint2 vA[8];
        float wA[8];
        {
            int r[8];
#pragma unroll
            for (int j = 0; j < 8; j++) r[j] = csr_src[k + j];
#pragma unroll
            for (int j = 0; j < 8; j++) vA[j] = h1v8[(size_t)r[j] * 16 + lane];
#pragma unroll
            for (int j = 0; j < 8; j++) wA[j] = h1s[r[j]];
        }
        k += 8;
        while (s1 - k >= 8) {
            uint2 vB[8];
            float wB[8];
            {
                int r[8];
#pragma unroll
                for (int j = 0; j < 8; j++) r[j] = csr_src[k + j];
#pragma unroll
                for (int j = 0; j < 8; j++) vB[j] = h1v8[(size_t)r[j] * 16 + lane];
#pragma unroll
                for (int j = 0; j < 8; j++) wB[j] = h1s[r[j]];
            }
            k += 8;
            fma8i8(a0, vA[0], wA[0]);
            fma8i8(a1, vA[1], wA[1]);
            fma8i8(a2, vA[2], wA[2]);
            fma8i8(a3, vA[3], wA[3]);
            fma8i8(a0, vA[4], wA[4]);
            fma8i8(a1, vA[5], wA[5]);
            fma8i8(a2, vA[6], wA[6]);
            fma8i8(a3, vA[7], wA[7]);
#pragma unroll
            for (int j = 0; j < 8; j++) { vA[j] = vB[j]; wA[j] = wB[j]; }
        }
        fma8i8(a0, vA[0], wA[0]);
        fma8i8(a1, vA[1], wA[1]);
        fma8i8(a2, vA[2], wA[2]);
        fma8i8(a3, vA[3], wA[3]);
        fma8i8(a0, vA[4], wA[4]);
        fma8i8(a1, vA[5], wA[5]);
        fma8i8(a2, vA[6], wA[6]);
        fma8i8(a3, vA[7], wA[7]);
    }
    int m = s1 - k;
    if (m > 0) {
        int r[8];
#pragma unroll
        for (int j = 0; j < 8; j++) r[j] = csr_src[j < m ? k + j : k];
        uint2 v[8];
#pragma unroll
        for (int j = 0; j < 8; j++) v[j] = h1v8[(size_t)r[j] * 16 + lane];
        float w[8];
#pragma unroll
        for (int j = 0; j < 8; j++) w[j] = (j < m) ? h1s[r[j]] : 0.f;
        fma8i8(a0, v[0], w[0]);
        fma8i8(a1, v[1], w[1]);
        fma8i8(a2, v[2], w[2]);
        fma8i8(a3, v[3], w[3]);
        fma8i8(a0, v[4], w[4]);
        fma8i8(a1, v[5], w[5]);
        fma8i8(a2, v[6], w[6]);
        fma8i8(a3, v[7], w[7]);
    }

    float dc = dinv[node];
    float4 bb0 = ((const float4*)b1p)[lane * 2];
    float4 bb1 = ((const float4*)b1p)[lane * 2 + 1];
    float o[8];
    o[0] = fmaxf(((a0[0] + a1[0]) + (a2[0] + a3[0])) * dc + bb0.x, 0.f);
    o[1] = fmaxf(((a0[1] + a1[1]) + (a2[1] + a3[1])) * dc + bb0.y, 0.f);
    o[2] = fmaxf(((a0[2] + a1[2]) + (a2[2] + a3[2])) * dc + bb0.z, 0.f);
    o[3] = fmaxf(((a0[3] + a1[3]) + (a2[3] + a3[3])) * dc + bb0.w, 0.f);
    o[4] = fmaxf(((a0[4] + a1[4]) + (a2[4] + a3[4])) * dc + bb1.x, 0.f);
    o[5] = fmaxf(((a0[5] + a1[5]) + (a2[5] + a3[5])) * dc + bb1.y, 0.f);
    o[6] = fmaxf(((a0[6] + a1[6]) + (a2[6] + a3[6])) * dc + bb1.z, 0.f);
    o[7] = fmaxf(((a0[7] + a1[7]) + (a2[7] + a3[7])) * dc + bb1.w, 0.f);
    uint4 pk;
    pk.x = pack_bf16(o[0], o[1]);
    pk.y = pack_bf16(o[2], o[3]);
    pk.z = pack_bf16(o[4], o[5]);
    pk.w = pack_bf16(o[6], o[7]);
    gb[(size_t)node * 16 + lane] = pk;
}

// ---------- GEMM2 via bf16 MFMA, LDS-free; fused es/ed; int8 h2 out ----------
// Epilogue quantizes h2 to int8 with one f32 scale/row (h2s). es/ed computed
// from the fp32 accumulators BEFORE quant, so softmax weights stay exact.
// Stored-byte order matches the old stored-bf16 linear order (pcol convention):
// lane l16 writes ushort pairs at indices l16 (cols 2*l16, 2*l16+1) and
// 16+l16 (cols 32+2*l16, 33+2*l16) of the 64-byte row.
__global__ __launch_bounds__(256) void gemm2_mfma(const uint4* __restrict__ gb4,
                                                  const uint4* __restrict__ wg2frag,
                                                  const float* __restrict__ a_src,
                                                  const float* __restrict__ a_dst,
                                                  unsigned char* __restrict__ h2q,
                                                  float* __restrict__ h2s,
                                                  float* __restrict__ es,
                                                  float* __restrict__ ed, int M) {
    const int t = threadIdx.x;
    const int wave = t >> 6;
    const int lane = t & 63;
    const int l16 = lane & 15;
    const int quad = lane >> 4;
    const int rowbase = blockIdx.x * 64 + wave * 16;

    int arow = rowbase + l16;
    if (arow >= M) arow = M - 1;

    f32x4 acc[4];
#pragma unroll
    for (int nt = 0; nt < 4; nt++) acc[nt] = (f32x4){0.f, 0.f, 0.f, 0.f};

#pragma unroll
    for (int c = 0; c < 4; c++) {
        uint4 au = gb4[(size_t)arow * 16 + c * 4 + quad];
        bf16x8 a = __builtin_bit_cast(bf16x8, au);
#pragma unroll
        for (int nt = 0; nt < 4; nt++) {
            uint4 bu = wg2frag[(size_t)((c * 64 + nt * 16 + l16) * 4 + quad)];
            bf16x8 b = __builtin_bit_cast(bf16x8, bu);
            acc[nt] = __builtin_amdgcn_mfma_f32_16x16x32_bf16(a, b, acc[nt], 0, 0, 0);
        }
    }

    float as0 = a_src[l16], as1 = a_src[16 + l16], as2 = a_src[32 + l16], as3 = a_src[48 + l16];
    float ad0 = a_dst[l16], ad1 = a_dst[16 + l16], ad2 = a_dst[32 + l16], ad3 = a_dst[48 + l16];

#pragma unroll
    for (int r = 0; r < 4; r++) {
        int row = rowbase + quad * 4 + r;
        float ps = acc[0][r] * as0 + acc[1][r] * as1 + acc[2][r] * as2 + acc[3][r] * as3;
        float pd = acc[0][r] * ad0 + acc[1][r] * ad1 + acc[2][r] * ad2 + acc[3][r] * ad3;
#pragma unroll
        for (int m = 8; m; m >>= 1) {
            ps += __shfl_xor(ps, m, 16);
            pd += __shfl_xor(pd, m, 16);
        }
        // row-max for int8 quant (row uniform over the 16 l16-lanes -> convergent)
        float gm = fmaxf(fmaxf(fabsf(acc[0][r]), fabsf(acc[1][r])),
                         fmaxf(fabsf(acc[2][r]), fabsf(acc[3][r])));
        gm = fmaxf(gm, __shfl_xor(gm, 1, 16));
        gm = fmaxf(gm, __shfl_xor(gm, 2, 16));
        gm = fmaxf(gm, __shfl_xor(gm, 4, 16));
        gm = fmaxf(gm, __shfl_xor(gm, 8, 16));
        float inv = gm > 0.f ? 127.0f / gm : 0.f;
        if (row < M) {
            int q0 = (int)rintf(acc[0][r] * inv);
            int q1 = (int)rintf(acc[1][r] * inv);
            int q2 = (int)rintf(acc[2][r] * inv);
            int q3 = (int)rintf(acc[3][r] * inv);
            unsigned short* hq = (unsigned short*)(h2q + (size_t)row * 64);
            hq[l16]      = (unsigned short)((q0 & 0xff) | ((q1 & 0xff) << 8));
            hq[16 + l16] = (unsigned short)((q2 & 0xff) | ((q3 & 0xff) << 8));
            if (l16 == 0) { es[row] = ps; ed[row] = pd; h2s[row] = gm * (1.0f / 127.0f); }
        }
    }
}

// ---------- fused GAT: 16 lanes/node, int8 h2 payload (64 B/row), deep pipeline ----------
// Payload footprint 6.4 MB -> high per-XCD L2 hit rate. Softmax denominator
// uses exact es (ssum += xv); value accumulate uses xv * h2s[r] on int8.
__global__ __launch_bounds__(256) void gat_fused(const int* __restrict__ offsets,
                                                 const int* __restrict__ csr_src,
                                                 const unsigned* __restrict__ h2q32,  // row = 16 uint
                                                 const float* __restrict__ h2s,
                                                 const float* __restrict__ es,
                                                 const float* __restrict__ ed,
                                                 const float* __restrict__ bgp,
                                                 const float2* __restrict__ wfcp,
                                                 const float* __restrict__ bfc,
                                                 float* __restrict__ out, int n) {
    int node = (blockIdx.x * 256 + threadIdx.x) >> 4;
    int lane = threadIdx.x & 15;
    if (node >= n) return;
    int s0 = offsets[node], s1 = offsets[node + 1];
    float edc = ed[node];

    float x0s = lexp(es[node] + edc);
    float sA = x0s, sB = 0.f, sC = 0.f, sD = 0.f;
    float aA[4], aB[4], aC[4], aD[4];
#pragma unroll
    for (int i = 0; i < 4; i++) { aA[i] = 0.f; aB[i] = 0.f; aC[i] = 0.f; aD[i] = 0.f; }
    fma4i8(aA, h2q32[(size_t)node * 16 + lane], x0s * h2s[node]);   // self loop

    int k = s0;
    if (s1 - k >= 8) {
        unsigned vA[8];
        float eA[8], hA[8];
        {
            int r[8];
#pragma unroll
            for (int j = 0; j < 8; j++) r[j] = csr_src[k + j];
#pragma unroll
            for (int j = 0; j < 8; j++) vA[j] = h2q32[(size_t)r[j] * 16 + lane];
#pragma unroll
            for (int j = 0; j < 8; j++) eA[j] = es[r[j]];
#pragma unroll
            for (int j = 0; j < 8; j++) hA[j] = h2s[r[j]];
        }
        k += 8;
        while (s1 - k >= 8) {
            unsigned vB[8];
            float eB[8], hB[8];
            {
                int r[8];
#pragma unroll
                for (int j = 0; j < 8; j++) r[j] = csr_src[k + j];
#pragma unroll
                for (int j = 0; j < 8; j++) vB[j] = h2q32[(size_t)r[j] * 16 + lane];
#pragma unroll
                for (int j = 0; j < 8; j++) eB[j] = es[r[j]];
#pragma unroll
                for (int j = 0; j < 8; j++) hB[j] = h2s[r[j]];
            }
            k += 8;
            float x0 = lexp(eA[0] + edc), x1 = lexp(eA[1] + edc);
            float x2 = lexp(eA[2] + edc), x3 = lexp(eA[3] + edc);
            float x4 = lexp(eA[4] + edc), x5 = lexp(eA[5] + edc);
            float x6 = lexp(eA[6] + edc), x7 = lexp(eA[7] + edc);
            sA += x0; sB += x1; sC += x2; sD += x3;
            sA += x4; sB += x5; sC += x6; sD += x7;
            fma4i8(aA, vA[0], x0 * hA[0]);
            fma4i8(aB, vA[1], x1 * hA[1]);
            fma4i8(aC, vA[2], x2 * hA[2]);
            fma4i8(aD, vA[3], x3 * hA[3]);
            fma4i8(aA, vA[4], x4 * hA[4]);
            fma4i8(aB, vA[5], x5 * hA[5]);
            fma4i8(aC, vA[6], x6 * hA[6]);
            fma4i8(aD, vA[7], x7 * hA[7]);
#pragma unroll
            for (int j = 0; j < 8; j++) { vA[j] = vB[j]; eA[j] = eB[j]; hA[j] = hB[j]; }
        }
        float x0 = lexp(eA[0] + edc), x1 = lexp(eA[1] + edc);
        float x2 = lexp(eA[2] + edc), x3 = lexp(eA[3] + edc);
        float x4 = lexp(eA[4] + edc), x5 = lexp(eA[5] + edc);
        float x6 = lexp(eA[6] + edc), x7 = lexp(eA[7] + edc);
        sA += x0; sB += x1; sC += x2; sD += x3;
        sA += x4; sB += x5; sC += x6; sD += x7;
        fma4i8(aA, vA[0], x0 * hA[0]);
        fma4i8(aB, vA[1], x1 * hA[1]);
        fma4i8(aC, vA[2], x2 * hA[2]);
        fma4i8(aD, vA[3], x3 * hA[3]);
        fma4i8(aA, vA[4], x4 * hA[4]);
        fma4i8(aB, vA[5], x5 * hA[5]);
        fma4i8(aC, vA[6], x6 * hA[6]);
        fma4i8(aD, vA[7], x7 * hA[7]);
    }
    int m = s1 - k;
    if (m > 0) {
        // predicated tail batch: all loads issued back-to-back, weight 0 for pads
        int r[8];
#pragma unroll
        for (int j = 0; j < 8; j++) r[j] = csr_src[j < m ? k + j : k];
        unsigned v[8];
#pragma unroll
        for (int j = 0; j < 8; j++) v[j] = h2q32[(size_t)r[j] * 16 + lane];
        float ev[8], hv[8];
#pragma unroll
        for (int j = 0; j < 8; j++) ev[j] = es[r[j]];
#pragma unroll
        for (int j = 0; j < 8; j++) hv[j] = h2s[r[j]];
        float x0 = (0 < m) ? lexp(ev[0] + edc) : 0.f;
        float x1 = (1 < m) ? lexp(ev[1] + edc) : 0.f;
        float x2 = (2 < m) ? lexp(ev[2] + edc) : 0.f;
        float x3 = (3 < m) ? lexp(ev[3] + edc) : 0.f;
        float x4 = (4 < m) ? lexp(ev[4] + edc) : 0.f;
        float x5 = (5 < m) ? lexp(ev[5] + edc) : 0.f;
        float x6 = (6 < m) ? lexp(ev[6] + edc) : 0.f;
        float x7 = (7 < m) ? lexp(ev[7] + edc) : 0.f;
        sA += x0; sB += x1; sC += x2; sD += x3;
        sA += x4; sB += x5; sC += x6; sD += x7;
        fma4i8(aA, v[0], x0 * hv[0]);
        fma4i8(aB, v[1], x1 * hv[1]);
        fma4i8(aC, v[2], x2 * hv[2]);
        fma4i8(aD, v[3], x3 * hv[3]);
        fma4i8(aA, v[4], x4 * hv[4]);
        fma4i8(aB, v[5], x5 * hv[5]);
        fma4i8(aC, v[6], x6 * hv[6]);
        fma4i8(aD, v[7], x7 * hv[7]);
    }

    float s = (sA + sB) + (sC + sD);
    float rcp = 1.0f / s;
    float4 bb = ((const float4*)bgp)[lane];       // bgp[4*lane .. 4*lane+3]
    float o[4];
    o[0] = fmaxf(((aA[0] + aB[0]) + (aC[0] + aD[0])) * rcp + bb.x, 0.f);
    o[1] = fmaxf(((aA[1] + aB[1]) + (aC[1] + aD[1])) * rcp + bb.y, 0.f);
    o[2] = fmaxf(((aA[2] + aB[2]) + (aC[2] + aD[2])) * rcp + bb.z, 0.f);
    o[3] = fmaxf(((aA[3] + aB[3]) + (aC[3] + aD[3])) * rcp + bb.w, 0.f);

    // FC: lane owns stored cols 4*lane..4*lane+3; wfcp[i] = (Wfc[pcol(i)][0], [1])
    float4 w01 = ((const float4*)wfcp)[lane * 2];      // wfcp[4l], wfcp[4l+1]
    float4 w23 = ((const float4*)wfcp)[lane * 2 + 1];  // wfcp[4l+2], wfcp[4l+3]
    float p0 = o[0] * w01.x + o[1] * w01.z + o[2] * w23.x + o[3] * w23.z;
    float p1 = o[0] * w01.y + o[1] * w01.w + o[2] * w23.y + o[3] * w23.w;
#pragma unroll
    for (int mm = 8; mm; mm >>= 1) {
        p0 += __shfl_xor(p0, mm, 16);
        p1 += __shfl_xor(p1, mm, 16);
    }
    if (lane == 0) {
        out[(size_t)node * 2 + 0] = p0 + bfc[0];
        out[(size_t)node * 2 + 1] = p1 + bfc[1];
    }
}

extern "C" void kernel_launch(void* const* d_in, const int* in_sizes, int n_in,
                              void* d_out, int out_size, void* d_ws, size_t ws_size,
                              hipStream_t stream) {
    const float* x     = (const float*)d_in[0];
    const int*   ei    = (const int*)d_in[1];
    const float* W1    = (const float*)d_in[2];
    const float* b1    = (const float*)d_in[3];
    const float* Wg    = (const float*)d_in[4];
    const float* a_src = (const float*)d_in[5];
    const float* a_dst = (const float*)d_in[6];
    const float* bg    = (const float*)d_in[7];
    const float* Wfc   = (const float*)d_in[8];
    const float* bfc   = (const float*)d_in[9];
    float* out = (float*)d_out;

    const int N = in_sizes[0] / IN_DIM;
    const int E = in_sizes[1] / 2;
    const int* rowi = ei;
    const int* coli = ei + E;
    const int ncb = (N + 255) >> 8;            // coarse buckets of 256 nodes

    auto alignup = [](char* p) { return (char*)(((uintptr_t)p + 15) & ~(uintptr_t)15); };

    // workspace layout
    char* wsb = (char*)d_ws;
    int*   offsets = (int*)wsb;                         // N+8
    float* dinv    = (float*)(offsets + N + 8);         // N
    float* es      = dinv + N;                          // N
    float* ed      = es + N;                            // N
    float* h1s     = ed + N;                            // N (f32 row scales, L2-resident)
    float* h2s     = h1s + N;                           // N (f32 h2 row scales)
    int*   ghist   = (int*)(h2s + N);                   // NCB_MAX
    int*   cstart  = ghist + NCB_MAX;                   // NCB_MAX+2
    int*   gcursor = cstart + NCB_MAX + 2;              // NCB_MAX
    float* b1p     = (float*)(gcursor + NCB_MAX);       // 128
    float* bgp     = b1p + 128;                         // 64
    float2* wfcp   = (float2*)(bgp + 64);               // 64 float2
    uint4* wfrag   = (uint4*)alignup((char*)(wfcp + 64));   // 3072 uint4 (48 KB)
    uint4* wg2frag = wfrag + 3072;                      // 1024 uint4 (16 KB)
    int*   csr_src = (int*)(wg2frag + 1024);            // E
    unsigned* ebuf = (unsigned*)(csr_src + E);          // E (packed row<<8|local)
    unsigned char* h1p8 = (unsigned char*)alignup((char*)(ebuf + E)); // N*128 bytes (int8, perm)
    uint4* gb      = (uint4*)alignup((char*)(h1p8 + (size_t)N * 128)); // N*16 uint4
    unsigned char* h2q = h1p8;  // alias: h1p8 dead after gcn_gather; h2q = N*64 bytes

    hipMemsetAsync(ghist, 0, NCB_MAX * 4, stream);

    const int nbE = (E + EPB - 1) / EPB;

    // 1) CSR build: coarse hist -> scan -> privatized scatter -> fused fine pass
    chist<<<nbE, 256, 0, stream>>>(coli, E, ghist, ncb);
    cscan<<<1, NCB_MAX, 0, stream>>>(ghist, cstart, gcursor, ncb, E);
    pass1_scatter<<<nbE, 256, 0, stream>>>(rowi, coli, E, gcursor, ebuf, ncb);
    pass2_all<<<ncb, 256, 0, stream>>>(ebuf, cstart, offsets, dinv, csr_src, N, E);

    // 2) weight prep (single dispatch)
    wprep_all<<<16, 256, 0, stream>>>(W1, b1, Wg, bg, Wfc, wfrag, b1p, wg2frag, bgp, wfcp);

    // 3) h1p8 = int8-row-quant((x @ W1) * dinv[row]) via LDS-free MFMA
    gemm1_mfma<<<(N + 63) / 64, 256, 0, stream>>>(x, wfrag, dinv, h1p8, h1s, N);

    // 4) GCN gather (int8 payload + L2-resident f32 row scales) -> bf16 g (perm layout)
    gcn_gather<<<(N + 15) / 16, 256, 0, stream>>>(offsets, csr_src, (const uint2*)h1p8,
                                                  h1s, dinv, b1p, gb, N);

    // 5) h2q = int8-row-quant(g @ Wg) via LDS-free MFMA, fused exact es/ed epilogue
    gemm2_mfma<<<(N + 63) / 64, 256, 0, stream>>>(gb, wg2frag, a_src, a_dst, h2q, h2s,
                                                  es, ed, N);

    // 6) fused GAT: 16 lanes/node, int8 h2 payload, deep-pipelined gather + FC
    gat_fused<<<(N + 15) / 16, 256, 0, stream>>>(offsets, csr_src, (const unsigned*)h2q,
                                                 h2s, es, ed, bgp, wfcp, bfc, out, N);
}